// Round 1
// baseline (662.827 us; speedup 1.0000x reference)
//
#include <hip/hip_runtime.h>
#include <hip/hip_cooperative_groups.h>

namespace cg = cooperative_groups;

#define NS 512
#define DF 512
#define NQ 16384

// ws layout (float offsets)
#define WS_MEAN0 0
#define WS_MEAN1 512
#define WS_MEANA 1024
#define WS_CNT   1536
#define WS_V0    2048
#define WS_V1    2560
#define WS_KC    3072
#define WS_M     4096                      // M / P fp32 [2][512][512]
#define WS_PB    (WS_M + 2*DF*DF)          // P bf16 [2][512][512] (as ushort)
#define WS_QB    (WS_PB + DF*DF)           // Q bf16 [16384][512] (ushort); ALSO Gram partials earlier
#define WS_GP    WS_QB                     // Gp [8 chunks][2 cls][512][512] f32 = 16MB (consumed before k_qinit overwrites)

typedef __attribute__((ext_vector_type(8))) short short8;
typedef __attribute__((ext_vector_type(4))) float floatx4;

__device__ __forceinline__ unsigned short f2bf(float f) {
    unsigned u = __float_as_uint(f);
    unsigned r = (u + 0x7fffu + ((u >> 16) & 1u)) >> 16;
    return (unsigned short)r;
}

// readlane for float: raw builtin takes i32 -> bitcast explicitly (R5 bug).
__device__ __forceinline__ float readlane_f(float v, int lane) {
    return __uint_as_float(__builtin_amdgcn_readlane(__float_as_uint(v), lane));
}

__device__ __forceinline__ void load_lds16(const void* g, void* l) {
    __builtin_amdgcn_global_load_lds(
        (const __attribute__((address_space(1))) unsigned int*)g,
        (__attribute__((address_space(3))) unsigned int*)l, 16, 0, 0);
}

// ---------------- fused front-end: stats + gram + asm + 8x GJ + vk ----------------
// One cooperative kernel, 256 blocks x 256 threads (1 block/CU, guaranteed
// co-resident: 52 KB LDS <= 160 KB). grid.sync() replaces 11 kernel
// boundaries of the previous 12-dispatch chain.
struct SGram { float SA[16 * 65]; float SB[16 * 65]; int lb[16]; };
struct SStats { int lb[NS]; float r0[4][64]; float r1[4][64]; int rc[4]; };
struct SGJ { float T[64 * 65]; float LV[64 * 65]; float LU[64 * 33]; float D1[64 * 33]; float rbuf[2][4][64]; };
struct SVk { float ml[DF]; float red[4][64]; };
union SMem { SGram gr; SStats st; SGJ gj; SVk vk; };   // max = SGJ = 52224 B

__global__ __launch_bounds__(256) void k_mega(const float* __restrict__ S,
                                              const int* __restrict__ lab,
                                              float* __restrict__ ws) {
    cg::grid_group grid = cg::this_grid();
    __shared__ SMem sm;
    const int b = blockIdx.x;
    const int tid = threadIdx.x;

    // ---------- phase 0a: class stats (blocks 0..7; 4 row-chunks of 128) ----------
    if (b < 8) {
        for (int l = tid; l < NS; l += 256) sm.st.lb[l] = lab[l];
        __syncthreads();
        int dl = tid & 63, ch = tid >> 6;          // ch 0..3
        int dd = b * 64 + dl;
        float s0 = 0.f, s1 = 0.f;
        int n1 = 0;
        for (int n = ch * 128; n < ch * 128 + 128; ++n) {
            float v = S[n * DF + dd];
            if (sm.st.lb[n]) { s1 += v; n1++; } else { s0 += v; }
        }
        sm.st.r0[ch][dl] = s0; sm.st.r1[ch][dl] = s1;
        if (dl == 0) sm.st.rc[ch] = n1;
        __syncthreads();
        if (ch == 0) {
            float t0 = 0.f, t1 = 0.f; int n1t = 0;
#pragma unroll
            for (int x = 0; x < 4; ++x) { t0 += sm.st.r0[x][dl]; t1 += sm.st.r1[x][dl]; n1t += sm.st.rc[x]; }
            float fn1 = (float)n1t, fn0 = (float)(NS - n1t);
            ws[WS_MEAN0 + dd] = t0 / fn0;
            ws[WS_MEAN1 + dd] = t1 / fn1;
            ws[WS_MEANA + dd] = (t0 + t1) / (float)NS;
            if (b == 0 && dl == 0) {
                ws[WS_CNT] = fn0; ws[WS_CNT + 1] = fn1;
                ws[WS_KC] = 0.f; ws[WS_KC + 1] = 0.f;
            }
        }
        __syncthreads();   // LDS overlay boundary (st -> gr)
    }

    // ---------- phase 0b: masked partial Grams (all blocks, 2 jobs each) ----------
    {
        int tx = tid & 15, ty = tid >> 4;
        float* Gp = ws + WS_GP;
        for (int jj = 0; jj < 2; ++jj) {
            int job = b + jj * 256;                        // 512 jobs == old (8,8,8) grid
            int i0 = (job & 7) * 64, j0 = ((job >> 3) & 7) * 64, z = job >> 6;
            float a0[4][4] = {{0.f}}, a1[4][4] = {{0.f}};
            for (int nc = z * 64; nc < z * 64 + 64; nc += 16) {
#pragma unroll
                for (int l = 0; l < 4; ++l) {
                    int idx = tid + 256 * l;
                    int nn = idx >> 6, col = idx & 63;
                    sm.gr.SA[nn * 65 + col] = S[(nc + nn) * DF + i0 + col];
                    sm.gr.SB[nn * 65 + col] = S[(nc + nn) * DF + j0 + col];
                }
                if (tid < 16) sm.gr.lb[tid] = lab[nc + tid];
                __syncthreads();
#pragma unroll
                for (int kk = 0; kk < 16; ++kk) {
                    float av[4], bv[4];
#pragma unroll
                    for (int r = 0; r < 4; ++r) av[r] = sm.gr.SA[kk * 65 + ty * 4 + r];
#pragma unroll
                    for (int s = 0; s < 4; ++s) bv[s] = sm.gr.SB[kk * 65 + tx * 4 + s];
                    if (sm.gr.lb[kk]) {
#pragma unroll
                        for (int r = 0; r < 4; ++r)
#pragma unroll
                            for (int s = 0; s < 4; ++s) a1[r][s] += av[r] * bv[s];
                    } else {
#pragma unroll
                        for (int r = 0; r < 4; ++r)
#pragma unroll
                            for (int s = 0; s < 4; ++s) a0[r][s] += av[r] * bv[s];
                    }
                }
                __syncthreads();
            }
#pragma unroll
            for (int r = 0; r < 4; ++r) {
                int i = i0 + ty * 4 + r;
#pragma unroll
                for (int s = 0; s < 4; ++s) {
                    int j = j0 + tx * 4 + s;
                    Gp[((z * 2 + 0) * DF + i) * DF + j] = a0[r][s];
                    Gp[((z * 2 + 1) * DF + i) * DF + j] = a1[r][s];
                }
            }
        }
    }
    grid.sync();

    // ---------- phase 1: assemble M_c (4 units/block == old 1024-block k_asm) ----------
    {
        const float* Gp = ws + WS_GP;
        float n0 = ws[WS_CNT], n1 = ws[WS_CNT + 1];
        float lam0 = fminf(n0 / (n0 + 1.f), 0.1f);
        float lam1 = fminf(n1 / (n1 + 1.f), 0.1f);
#pragma unroll
        for (int u = 0; u < 4; ++u) {
            int e = (b * 4 + u) * 256 + tid;
            int i = e >> 9, j = e & 511;
            float g0 = 0.f, g1 = 0.f;
#pragma unroll
            for (int ch = 0; ch < 8; ++ch) {
                g0 += Gp[((ch * 2 + 0) * DF + i) * DF + j];
                g1 += Gp[((ch * 2 + 1) * DF + i) * DF + j];
            }
            float m0i = ws[WS_MEAN0 + i], m1i = ws[WS_MEAN1 + i], mai = ws[WS_MEANA + i];
            float m0j = ws[WS_MEAN0 + j], m1j = ws[WS_MEAN1 + j], maj = ws[WS_MEANA + j];
            float task = (g0 + g1 - (float)NS * mai * maj) / (float)(NS - 1);
            float cov0 = (g0 - n0 * m0i * m0j) / (n0 - 1.f);
            float cov1 = (g1 - n1 * m1i * m1j) / (n1 - 1.f);
            float dg = (i == j) ? 0.1f : 0.f;
            ws[WS_M + i * DF + j] = lam0 * cov0 + (1.f - lam0) * task + dg;
            ws[WS_M + DF * DF + i * DF + j] = lam1 * cov1 + (1.f - lam1) * task + dg;
        }
    }
    grid.sync();

    // ---------- phase 2: 8 fused Gauss-Jordan rounds (old 8x k_step launches) ----------
    {
        const int c = (b >> 6) & 1;
        const int jh = b >> 7;
        const int ti = (b & 63) >> 3, tj = b & 7;
        float* Mb = ws + WS_M + c * DF * DF;
        unsigned short* pb = (unsigned short*)(ws + WS_PB) + (size_t)c * DF * DF;
        const int jl = tid & 63, w = tid >> 6;

        for (int k = 0; k < 8; ++k) {
            const int wbf = (k == 7) ? 1 : 0;
            float* Akk = Mb + (k * 64) * DF + k * 64;
            bool isdiag = (ti == k) && (tj == k);
            bool isrow = (ti == k) && (tj != k);
            bool iscol = (tj == k) && (ti != k);

            // phase 2.0: global reads (all blocks start together post-sync)
#pragma unroll
            for (int m = 0; m < 16; ++m) {
                int idx = tid + 256 * m;
                int i = idx >> 6, j = idx & 63;
                sm.gj.T[i * 65 + j] = Akk[i * DF + j];
            }
            if (ti != k) {
                const float* src = Mb + (ti * 64) * DF + k * 64;   // V = A[ti][k]
#pragma unroll
                for (int m = 0; m < 16; ++m) {
                    int idx = tid + 256 * m;
                    int i = idx >> 6, j = idx & 63;
                    sm.gj.LV[i * 65 + j] = src[i * DF + j];
                }
            }
            if (tj != k) {
                const float* src = Mb + (k * 64) * DF + tj * 64 + jh * 32;  // U half-cols
#pragma unroll
                for (int m = 0; m < 8; ++m) {
                    int idx = tid + 256 * m;
                    int i = idx >> 5, j = idx & 31;
                    sm.gj.LU[i * 33 + j] = src[i * DF + j];
                }
            }
            __syncthreads();

            // phase 2.1: in-register GJ inversion of T, 4 pivots per round
            float Tr[16];
#pragma unroll
            for (int m = 0; m < 16; ++m) Tr[m] = sm.gj.T[(w * 16 + m) * 65 + jl];
#pragma unroll
            for (int r = 0; r < 16; ++r) {
                const int q0 = r * 4;
                const int par = r & 1;
                if (w == (q0 >> 4)) {
                    const int mb = q0 & 15;
                    sm.gj.rbuf[par][0][jl] = Tr[mb + 0];
                    sm.gj.rbuf[par][1][jl] = Tr[mb + 1];
                    sm.gj.rbuf[par][2][jl] = Tr[mb + 2];
                    sm.gj.rbuf[par][3][jl] = Tr[mb + 3];
                }
                __syncthreads();
                float B[4][4];
#pragma unroll
                for (int a = 0; a < 4; ++a)
#pragma unroll
                    for (int bb = 0; bb < 4; ++bb) B[a][bb] = sm.gj.rbuf[par][a][q0 + bb];
                // invert B in place (GJ, no pivoting: SPD principal block)
#pragma unroll
                for (int p = 0; p < 4; ++p) {
                    float piv = 1.0f / B[p][p];
#pragma unroll
                    for (int j = 0; j < 4; ++j) if (j != p) B[p][j] *= piv;
#pragma unroll
                    for (int i = 0; i < 4; ++i) if (i != p) {
                        float f = B[i][p];
#pragma unroll
                        for (int j = 0; j < 4; ++j) if (j != p) B[i][j] -= f * B[p][j];
                        B[i][p] = -f * piv;
                    }
                    B[p][p] = piv;
                }
                float r0v = sm.gj.rbuf[par][0][jl], r1v = sm.gj.rbuf[par][1][jl];
                float r2v = sm.gj.rbuf[par][2][jl], r3v = sm.gj.rbuf[par][3][jl];
                float nr[4];
#pragma unroll
                for (int a = 0; a < 4; ++a)
                    nr[a] = B[a][0] * r0v + B[a][1] * r1v + B[a][2] * r2v + B[a][3] * r3v;
                bool colin = ((jl >> 2) == r);
                int bsel = jl & 3;
                float Bc[4];
#pragma unroll
                for (int a = 0; a < 4; ++a)
                    Bc[a] = bsel == 0 ? B[a][0]
                          : (bsel == 1 ? B[a][1] : (bsel == 2 ? B[a][2] : B[a][3]));
#pragma unroll
                for (int m = 0; m < 16; ++m) {
                    float cv0 = readlane_f(Tr[m], q0 + 0);
                    float cv1 = readlane_f(Tr[m], q0 + 1);
                    float cv2 = readlane_f(Tr[m], q0 + 2);
                    float cv3 = readlane_f(Tr[m], q0 + 3);
                    float g = Tr[m] - (cv0 * nr[0] + cv1 * nr[1] + cv2 * nr[2] + cv3 * nr[3]);
                    bool rowin = (((w * 16 + m) >> 2) == r);
                    float gcol = -(cv0 * Bc[0] + cv1 * Bc[1] + cv2 * Bc[2] + cv3 * Bc[3]);
                    if (rowin) g = nr[m & 3];
                    if (colin) g = rowin ? Bc[m & 3] : gcol;
                    Tr[m] = g;
                }
            }
#pragma unroll
            for (int m = 0; m < 16; ++m) sm.gj.T[(w * 16 + m) * 65 + jl] = Tr[m];
            __syncthreads();

            // phase 2.2: col-half tile update. thread: 2 rows x 4 cols of 64x32
            int tx8 = tid & 7, ty32 = tid >> 3;
            int cb0 = jh * 32;
            if (isdiag) {
#pragma unroll
                for (int m = 0; m < 8; ++m) {
                    int idx = tid + 256 * m;
                    int i = idx >> 5, j = idx & 31;
                    float v = sm.gj.T[i * 65 + cb0 + j];
                    Akk[i * DF + cb0 + j] = v;
                    if (wbf) pb[(size_t)(k * 64 + i) * DF + k * 64 + cb0 + j] = f2bf(v);
                }
            } else if (isrow) {
                float acc[2][4] = {{0.f}};
#pragma unroll 4
                for (int kk = 0; kk < 64; ++kk) {
                    float av[2], bv[4];
#pragma unroll
                    for (int r = 0; r < 2; ++r) av[r] = sm.gj.T[(ty32 * 2 + r) * 65 + kk];
#pragma unroll
                    for (int s = 0; s < 4; ++s) bv[s] = sm.gj.LU[kk * 33 + tx8 * 4 + s];
#pragma unroll
                    for (int r = 0; r < 2; ++r)
#pragma unroll
                        for (int s = 0; s < 4; ++s) acc[r][s] += av[r] * bv[s];
                }
                float* dst = Mb + (k * 64) * DF + tj * 64 + cb0;
#pragma unroll
                for (int r = 0; r < 2; ++r)
#pragma unroll
                    for (int s = 0; s < 4; ++s) {
                        float v = acc[r][s];
                        dst[(ty32 * 2 + r) * DF + tx8 * 4 + s] = v;
                        if (wbf) pb[(size_t)(k * 64 + ty32 * 2 + r) * DF + tj * 64 + cb0 + tx8 * 4 + s] = f2bf(v);
                    }
            } else if (iscol) {
                float acc[2][4] = {{0.f}};
#pragma unroll 4
                for (int kk = 0; kk < 64; ++kk) {
                    float av[2], bv[4];
#pragma unroll
                    for (int r = 0; r < 2; ++r) av[r] = sm.gj.LV[(ty32 * 2 + r) * 65 + kk];
#pragma unroll
                    for (int s = 0; s < 4; ++s) bv[s] = sm.gj.T[kk * 65 + cb0 + tx8 * 4 + s];
#pragma unroll
                    for (int r = 0; r < 2; ++r)
#pragma unroll
                        for (int s = 0; s < 4; ++s) acc[r][s] += av[r] * bv[s];
                }
                float* dst = Mb + (ti * 64) * DF + k * 64 + cb0;
#pragma unroll
                for (int r = 0; r < 2; ++r)
#pragma unroll
                    for (int s = 0; s < 4; ++s) {
                        float v = -acc[r][s];
                        dst[(ty32 * 2 + r) * DF + tx8 * 4 + s] = v;
                        if (wbf) pb[(size_t)(ti * 64 + ty32 * 2 + r) * DF + k * 64 + cb0 + tx8 * 4 + s] = f2bf(v);
                    }
            } else {
                // D1 = P * U_half (64x32)
                float a1[2][4] = {{0.f}};
#pragma unroll 4
                for (int kk = 0; kk < 64; ++kk) {
                    float av[2], bv[4];
#pragma unroll
                    for (int r = 0; r < 2; ++r) av[r] = sm.gj.T[(ty32 * 2 + r) * 65 + kk];
#pragma unroll
                    for (int s = 0; s < 4; ++s) bv[s] = sm.gj.LU[kk * 33 + tx8 * 4 + s];
#pragma unroll
                    for (int r = 0; r < 2; ++r)
#pragma unroll
                        for (int s = 0; s < 4; ++s) a1[r][s] += av[r] * bv[s];
                }
                __syncthreads();
#pragma unroll
                for (int r = 0; r < 2; ++r)
#pragma unroll
                    for (int s = 0; s < 4; ++s) sm.gj.D1[(ty32 * 2 + r) * 33 + tx8 * 4 + s] = a1[r][s];
                __syncthreads();
                // Y_half -= V * D1
                float a2[2][4] = {{0.f}};
#pragma unroll 4
                for (int kk = 0; kk < 64; ++kk) {
                    float av[2], bv[4];
#pragma unroll
                    for (int r = 0; r < 2; ++r) av[r] = sm.gj.LV[(ty32 * 2 + r) * 65 + kk];
#pragma unroll
                    for (int s = 0; s < 4; ++s) bv[s] = sm.gj.D1[kk * 33 + tx8 * 4 + s];
#pragma unroll
                    for (int r = 0; r < 2; ++r)
#pragma unroll
                        for (int s = 0; s < 4; ++s) a2[r][s] += av[r] * bv[s];
                }
                float* dst = Mb + (ti * 64) * DF + tj * 64 + cb0;
#pragma unroll
                for (int r = 0; r < 2; ++r)
#pragma unroll
                    for (int s = 0; s < 4; ++s) {
                        int off = (ty32 * 2 + r) * DF + tx8 * 4 + s;
                        float nv = dst[off] - a2[r][s];
                        dst[off] = nv;
                        if (wbf) pb[(size_t)(ti * 64 + ty32 * 2 + r) * DF + tj * 64 + cb0 + tx8 * 4 + s] = f2bf(nv);
                    }
            }
            grid.sync();
        }
    }

    // ---------- phase 3: v_c = P_c m_c, k_c = m^T v (blocks 0..15) ----------
    if (b < 16) {
        int c = b >> 3, rb = b & 7;
        const float* P = ws + WS_M + c * DF * DF;
        const float* mc = ws + (c ? WS_MEAN1 : WS_MEAN0);
        float* v = ws + (c ? WS_V1 : WS_V0);
        for (int l = tid; l < DF; l += 256) sm.vk.ml[l] = mc[l];
        __syncthreads();
        int rl = tid & 63, ch = tid >> 6;
        int row = rb * 64 + rl;
        float dot = 0.f;
        const float* pr = P + (size_t)row * DF + ch * 128;
        for (int t = 0; t < 32; ++t) {
            float4 pv = *(const float4*)(pr + t * 4);
            const float* mm = sm.vk.ml + ch * 128 + t * 4;
            dot += pv.x * mm[0] + pv.y * mm[1] + pv.z * mm[2] + pv.w * mm[3];
        }
        sm.vk.red[ch][rl] = dot;
        __syncthreads();
        if (ch == 0) {
            float d = sm.vk.red[0][rl] + sm.vk.red[1][rl] + sm.vk.red[2][rl] + sm.vk.red[3][rl];
            v[row] = d;
            float kp = d * sm.vk.ml[row];
#pragma unroll
            for (int off = 32; off > 0; off >>= 1) kp += __shfl_down(kp, off);
            if (rl == 0) atomicAdd(&ws[WS_KC + c], kp);
        }
    }
}

// ---------------- K5: fused Q->bf16 + logits init ----------------
__global__ __launch_bounds__(256) void k_qinit(const float* __restrict__ Q,
                                               float* __restrict__ ws,
                                               float* __restrict__ out) {
    unsigned short* qbw = (unsigned short*)(ws + WS_QB);
    const float* v0 = ws + WS_V0;
    const float* v1 = ws + WS_V1;
    int lane = threadIdx.x & 63;
    int q = blockIdx.x * 4 + (threadIdx.x >> 6);
    const float* qrow = Q + (size_t)q * DF + lane * 8;
    float4 x0 = *(const float4*)(qrow);
    float4 x1 = *(const float4*)(qrow + 4);
    const float* v0p = v0 + lane * 8;
    const float* v1p = v1 + lane * 8;
    float4 w00 = *(const float4*)(v0p), w01 = *(const float4*)(v0p + 4);
    float4 w10 = *(const float4*)(v1p), w11 = *(const float4*)(v1p + 4);
    float a0 = x0.x * w00.x + x0.y * w00.y + x0.z * w00.z + x0.w * w00.w
             + x1.x * w01.x + x1.y * w01.y + x1.z * w01.z + x1.w * w01.w;
    float a1 = x0.x * w10.x + x0.y * w10.y + x0.z * w10.z + x0.w * w10.w
             + x1.x * w11.x + x1.y * w11.y + x1.z * w11.z + x1.w * w11.w;
    short8 r;
    r[0] = (short)f2bf(x0.x); r[1] = (short)f2bf(x0.y);
    r[2] = (short)f2bf(x0.z); r[3] = (short)f2bf(x0.w);
    r[4] = (short)f2bf(x1.x); r[5] = (short)f2bf(x1.y);
    r[6] = (short)f2bf(x1.z); r[7] = (short)f2bf(x1.w);
    *(short8*)(qbw + (size_t)q * DF + lane * 8) = r;
#pragma unroll
    for (int off = 32; off > 0; off >>= 1) {
        a0 += __shfl_down(a0, off);
        a1 += __shfl_down(a1, off);
    }
    if (lane == 0) {
        out[q * 2 + 0] = 2.f * a0 - ws[WS_KC + 0];
        out[q * 2 + 1] = 2.f * a1 - ws[WS_KC + 1];
    }
}

// ---------------- K6: MFMA GEMM, 128x128 tile, LDS staging + swizzle ----------------
__global__ __launch_bounds__(256, 3) void k_gemm(const float* __restrict__ ws,
                                                 float* __restrict__ out) {
    const unsigned short* qb = (const unsigned short*)(ws + WS_QB);
    int c = blockIdx.y >> 2;
    int n0 = (blockIdx.y & 3) * 128;
    const unsigned short* pbc = (const unsigned short*)(ws + WS_PB) + (size_t)c * DF * DF;
    int q0 = blockIdx.x * 128;
    __shared__ __align__(16) unsigned short Abuf[128 * 64];   // 16 KB
    __shared__ __align__(16) unsigned short Bbuf[128 * 64];   // 16 KB
    int tid = threadIdx.x;
    int w = tid >> 6, lane = tid & 63;
    int quad = lane >> 4, l15 = lane & 15;
    floatx4 acc[2][8];
#pragma unroll
    for (int mt = 0; mt < 2; ++mt)
#pragma unroll
        for (int nt = 0; nt < 8; ++nt) acc[mt][nt] = (floatx4)(0.f);

    for (int kt = 0; kt < 8; ++kt) {
        int kc = kt * 64;
#pragma unroll
        for (int i = 0; i < 4; ++i) {
            int o = tid * 16 + i * 4096;
            int row = o >> 7;
            int sg = ((o >> 4) & 7) ^ (row & 7);
            load_lds16(qb + (size_t)(q0 + row) * DF + kc + sg * 8, (char*)Abuf + o);
        }
#pragma unroll
        for (int i = 0; i < 4; ++i) {
            int o = tid * 16 + i * 4096;
            int row = o >> 7;
            int sg = ((o >> 4) & 7) ^ (row & 7);
            load_lds16(pbc + (size_t)(n0 + row) * DF + kc + sg * 8, (char*)Bbuf + o);
        }
        __syncthreads();
#pragma unroll
        for (int kk2 = 0; kk2 < 2; ++kk2) {
            int u = ((kk2 * 4 + quad) ^ (l15 & 7)) << 4;   // swizzled 16B seg offset
            short8 bfrag[8];
#pragma unroll
            for (int nt = 0; nt < 8; ++nt)
                bfrag[nt] = *(const short8*)((const char*)Bbuf + (nt * 16 + l15) * 128 + u);
#pragma unroll
            for (int mt = 0; mt < 2; ++mt) {
                short8 a = *(const short8*)((const char*)Abuf + (w * 32 + mt * 16 + l15) * 128 + u);
#pragma unroll
                for (int nt = 0; nt < 8; ++nt)
                    acc[mt][nt] = __builtin_amdgcn_mfma_f32_16x16x32_bf16(a, bfrag[nt], acc[mt][nt], 0, 0, 0);
            }
        }
        __syncthreads();
    }
    // epilogue: partial row-dot with Q over this 128-col tile
#pragma unroll
    for (int mt = 0; mt < 2; ++mt)
#pragma unroll
        for (int reg = 0; reg < 4; ++reg) {
            int row = w * 32 + mt * 16 + quad * 4 + reg;
            float part = 0.f;
#pragma unroll
            for (int nt = 0; nt < 8; ++nt) {
                float h = acc[mt][nt][reg];
                unsigned qu = qb[(size_t)(q0 + row) * DF + n0 + nt * 16 + l15];
                part += h * __uint_as_float(qu << 16);
            }
            part += __shfl_xor(part, 1);
            part += __shfl_xor(part, 2);
            part += __shfl_xor(part, 4);
            part += __shfl_xor(part, 8);
            if (l15 == 0) atomicAdd(&out[(size_t)(q0 + row) * 2 + c], -part);
        }
}

extern "C" void kernel_launch(void* const* d_in, const int* in_sizes, int n_in,
                              void* d_out, int out_size, void* d_ws, size_t ws_size,
                              hipStream_t stream) {
    const float* S = (const float*)d_in[0];
    const int* lab = (const int*)d_in[1];
    const float* Q = (const float*)d_in[2];
    float* out = (float*)d_out;
    float* ws = (float*)d_ws;

    void* args[3] = {(void*)&S, (void*)&lab, (void*)&ws};
    hipLaunchCooperativeKernel((void*)k_mega, dim3(256), dim3(256), args, 0, stream);
    k_qinit<<<NQ / 4, 256, 0, stream>>>(Q, ws, out);
    k_gemm<<<dim3(NQ / 128, 8), 256, 0, stream>>>(ws, out);
}

// Round 2
// 387.446 us; speedup vs baseline: 1.7108x; 1.7108x over previous
//
#include <hip/hip_runtime.h>

#define NS 512
#define DF 512
#define NQ 16384

// ws layout (float offsets)
#define WS_MEAN0 0
#define WS_MEAN1 512
#define WS_MEANA 1024
#define WS_CNT   1536
#define WS_V0    2048
#define WS_V1    2560
#define WS_KC    3072
#define WS_M     4096                      // M / P fp32 [2][512][512]
#define WS_PB    (WS_M + 2*DF*DF)          // P bf16 [2][512][512] (as ushort)
#define WS_QB    (WS_PB + DF*DF)           // Q bf16 [16384][512] (ushort); ALSO Gram partials earlier
#define WS_GP    WS_QB                     // Gp [8 chunks][2 cls][512][512] f32 = 16MB (consumed by k_asm before k_qinit overwrites)

typedef __attribute__((ext_vector_type(8))) short short8;
typedef __attribute__((ext_vector_type(4))) float floatx4;

__device__ __forceinline__ unsigned short f2bf(float f) {
    unsigned u = __float_as_uint(f);
    unsigned r = (u + 0x7fffu + ((u >> 16) & 1u)) >> 16;
    return (unsigned short)r;
}

// readlane for float: the raw builtin takes i32 -> passing float would
// VALUE-convert (truncate!). Bitcast explicitly. (R5 bug.)
__device__ __forceinline__ float readlane_f(float v, int lane) {
    return __uint_as_float(__builtin_amdgcn_readlane(__float_as_uint(v), lane));
}

__device__ __forceinline__ void load_lds16(const void* g, void* l) {
    __builtin_amdgcn_global_load_lds(
        (const __attribute__((address_space(1))) unsigned int*)g,
        (__attribute__((address_space(3))) unsigned int*)l, 16, 0, 0);
}

// ---------------- K1: class stats (8 blocks x 512 thr) ----------------
__global__ __launch_bounds__(512) void k_stats(const float* __restrict__ S,
                                               const int* __restrict__ lab,
                                               float* __restrict__ ws) {
    __shared__ int lb[NS];
    __shared__ float r0[8][64], r1[8][64];
    __shared__ int rc[8];
    int tid = threadIdx.x;
    for (int l = tid; l < NS; l += 512) lb[l] = lab[l];
    __syncthreads();
    int dl = tid & 63, ch = tid >> 6;          // ch 0..7
    int dd = blockIdx.x * 64 + dl;
    float s0 = 0.f, s1 = 0.f;
    int n1 = 0;
    for (int n = ch * 64; n < ch * 64 + 64; ++n) {
        float v = S[n * DF + dd];
        if (lb[n]) { s1 += v; n1++; } else { s0 += v; }
    }
    r0[ch][dl] = s0; r1[ch][dl] = s1;
    if (dl == 0) rc[ch] = n1;
    __syncthreads();
    if (ch == 0) {
        float t0 = 0.f, t1 = 0.f; int n1t = 0;
#pragma unroll
        for (int x = 0; x < 8; ++x) { t0 += r0[x][dl]; t1 += r1[x][dl]; n1t += rc[x]; }
        float fn1 = (float)n1t, fn0 = (float)(NS - n1t);
        ws[WS_MEAN0 + dd] = t0 / fn0;
        ws[WS_MEAN1 + dd] = t1 / fn1;
        ws[WS_MEANA + dd] = (t0 + t1) / (float)NS;
        if (blockIdx.x == 0 && dl == 0) {
            ws[WS_CNT] = fn0; ws[WS_CNT + 1] = fn1;
            ws[WS_KC] = 0.f; ws[WS_KC + 1] = 0.f;
        }
    }
}

// ---------------- K2a: masked partial Grams (K-split x8) ----------------
__global__ __launch_bounds__(256) void k_gram_part(const float* __restrict__ S,
                                                   const int* __restrict__ lab,
                                                   float* __restrict__ ws) {
    __shared__ float SA[16 * 65];
    __shared__ float SB[16 * 65];
    __shared__ int lb[16];
    int tx = threadIdx.x, ty = threadIdx.y;
    int tid = ty * 16 + tx;
    int i0 = blockIdx.x * 64, j0 = blockIdx.y * 64;
    int z = blockIdx.z;
    float a0[4][4] = {{0.f}}, a1[4][4] = {{0.f}};
    for (int nc = z * 64; nc < z * 64 + 64; nc += 16) {
#pragma unroll
        for (int l = 0; l < 4; ++l) {
            int idx = tid + 256 * l;
            int nn = idx >> 6, col = idx & 63;
            SA[nn * 65 + col] = S[(nc + nn) * DF + i0 + col];
            SB[nn * 65 + col] = S[(nc + nn) * DF + j0 + col];
        }
        if (tid < 16) lb[tid] = lab[nc + tid];
        __syncthreads();
#pragma unroll
        for (int kk = 0; kk < 16; ++kk) {
            float av[4], bv[4];
#pragma unroll
            for (int r = 0; r < 4; ++r) av[r] = SA[kk * 65 + ty * 4 + r];
#pragma unroll
            for (int s = 0; s < 4; ++s) bv[s] = SB[kk * 65 + tx * 4 + s];
            if (lb[kk]) {
#pragma unroll
                for (int r = 0; r < 4; ++r)
#pragma unroll
                    for (int s = 0; s < 4; ++s) a1[r][s] += av[r] * bv[s];
            } else {
#pragma unroll
                for (int r = 0; r < 4; ++r)
#pragma unroll
                    for (int s = 0; s < 4; ++s) a0[r][s] += av[r] * bv[s];
            }
        }
        __syncthreads();
    }
    float* Gp = ws + WS_GP;
#pragma unroll
    for (int r = 0; r < 4; ++r) {
        int i = i0 + ty * 4 + r;
#pragma unroll
        for (int s = 0; s < 4; ++s) {
            int j = j0 + tx * 4 + s;
            Gp[((z * 2 + 0) * DF + i) * DF + j] = a0[r][s];
            Gp[((z * 2 + 1) * DF + i) * DF + j] = a1[r][s];
        }
    }
}

// ---------------- K2b: assemble M_c from partials ----------------
__global__ __launch_bounds__(256) void k_asm(float* __restrict__ ws) {
    const float* Gp = ws + WS_GP;
    int e = blockIdx.x * 256 + threadIdx.x;   // 0..262143
    int i = e >> 9, j = e & 511;
    float g0 = 0.f, g1 = 0.f;
#pragma unroll
    for (int ch = 0; ch < 8; ++ch) {
        g0 += Gp[((ch * 2 + 0) * DF + i) * DF + j];
        g1 += Gp[((ch * 2 + 1) * DF + i) * DF + j];
    }
    float n0 = ws[WS_CNT], n1 = ws[WS_CNT + 1];
    float lam0 = fminf(n0 / (n0 + 1.f), 0.1f);
    float lam1 = fminf(n1 / (n1 + 1.f), 0.1f);
    float m0i = ws[WS_MEAN0 + i], m1i = ws[WS_MEAN1 + i], mai = ws[WS_MEANA + i];
    float m0j = ws[WS_MEAN0 + j], m1j = ws[WS_MEAN1 + j], maj = ws[WS_MEANA + j];
    float task = (g0 + g1 - (float)NS * mai * maj) / (float)(NS - 1);
    float cov0 = (g0 - n0 * m0i * m0j) / (n0 - 1.f);
    float cov1 = (g1 - n1 * m1i * m1j) / (n1 - 1.f);
    float dg = (i == j) ? 0.1f : 0.f;
    ws[WS_M + i * DF + j] = lam0 * cov0 + (1.f - lam0) * task + dg;
    ws[WS_M + DF * DF + i * DF + j] = lam1 * cov1 + (1.f - lam1) * task + dg;
}

// ---------------- K3: fused Gauss-Jordan step (512 threads, 2 waves/SIMD) ----------------
// Phase 1 eliminates 4 pivots per barrier round; waves 4-7 duplicate waves
// 0-3's phase-1 work (w&3 mapping) so barrier counts stay uniform while the
// update phase uses all 8 waves with a 2x2 micro-tile per thread.
// LDS strides: T=66, LU/D1=34 -> float2 (ds_read_b64) B-operand reads,
// conflict-free (16 lanes x 8B span all 32 banks; wave64 2-way alias free).
__global__ __launch_bounds__(512) void k_step(float* __restrict__ ws, int k, int wbf) {
    int c = blockIdx.y;
    int jh = blockIdx.z;
    int ti = blockIdx.x >> 3, tj = blockIdx.x & 7;
    float* Mb = ws + WS_M + c * DF * DF;
    float* Akk = Mb + (k * 64) * DF + k * 64;
    unsigned short* pb = (unsigned short*)(ws + WS_PB) + (size_t)c * DF * DF;
    __shared__ float T[64 * 66];
    __shared__ float LV[64 * 65];
    __shared__ float LU[64 * 34];
    __shared__ float D1[64 * 34];
    __shared__ float rbuf[2][4][64];
    int tid = threadIdx.x;
    int jl = tid & 63, w = tid >> 6;          // w 0..7
    int w4 = w & 3;
    bool isdiag = (ti == k) && (tj == k);
    bool isrow = (ti == k) && (tj != k);
    bool iscol = (tj == k) && (ti != k);

    // phase 0: global reads
#pragma unroll
    for (int m = 0; m < 8; ++m) {
        int idx = tid + 512 * m;
        int i = idx >> 6, j = idx & 63;
        T[i * 66 + j] = Akk[i * DF + j];
    }
    if (ti != k) {
        const float* src = Mb + (ti * 64) * DF + k * 64;   // V = A[ti][k] (full)
#pragma unroll
        for (int m = 0; m < 8; ++m) {
            int idx = tid + 512 * m;
            int i = idx >> 6, j = idx & 63;
            LV[i * 65 + j] = src[i * DF + j];
        }
    }
    if (tj != k) {
        const float* src = Mb + (k * 64) * DF + tj * 64 + jh * 32;  // U half-cols
#pragma unroll
        for (int m = 0; m < 4; ++m) {
            int idx = tid + 512 * m;
            int i = idx >> 5, j = idx & 31;
            LU[i * 34 + j] = src[i * DF + j];
        }
    }
    __syncthreads();

    // phase 1: in-register GJ inversion, 4 pivots per round (all 8 waves,
    // waves 4-7 redundant via w4)
    float Tr[16];
#pragma unroll
    for (int m = 0; m < 16; ++m) Tr[m] = T[(w4 * 16 + m) * 66 + jl];
#pragma unroll
    for (int r = 0; r < 16; ++r) {
        const int q0 = r * 4;
        const int par = r & 1;
        if (w == (q0 >> 4)) {               // only waves 0..3 can match
            const int mb = q0 & 15;
            rbuf[par][0][jl] = Tr[mb + 0];
            rbuf[par][1][jl] = Tr[mb + 1];
            rbuf[par][2][jl] = Tr[mb + 2];
            rbuf[par][3][jl] = Tr[mb + 3];
        }
        __syncthreads();
        // 4x4 pivot block (wave-uniform values, broadcast LDS reads)
        float B[4][4];
#pragma unroll
        for (int a = 0; a < 4; ++a)
#pragma unroll
            for (int bb = 0; bb < 4; ++bb) B[a][bb] = rbuf[par][a][q0 + bb];
        // invert B in place (GJ, no pivoting: SPD principal block)
#pragma unroll
        for (int p = 0; p < 4; ++p) {
            float piv = 1.0f / B[p][p];
#pragma unroll
            for (int j = 0; j < 4; ++j) if (j != p) B[p][j] *= piv;
#pragma unroll
            for (int i = 0; i < 4; ++i) if (i != p) {
                float f = B[i][p];
#pragma unroll
                for (int j = 0; j < 4; ++j) if (j != p) B[i][j] -= f * B[p][j];
                B[i][p] = -f * piv;
            }
            B[p][p] = piv;
        }
        // new pivot rows evaluated at this thread's column jl
        float r0v = rbuf[par][0][jl], r1v = rbuf[par][1][jl];
        float r2v = rbuf[par][2][jl], r3v = rbuf[par][3][jl];
        float nr[4];
#pragma unroll
        for (int a = 0; a < 4; ++a)
            nr[a] = B[a][0] * r0v + B[a][1] * r1v + B[a][2] * r2v + B[a][3] * r3v;
        bool colin = ((jl >> 2) == r);
        int bsel = jl & 3;
        float Bc[4];
#pragma unroll
        for (int a = 0; a < 4; ++a)
            Bc[a] = bsel == 0 ? B[a][0]
                  : (bsel == 1 ? B[a][1] : (bsel == 2 ? B[a][2] : B[a][3]));
#pragma unroll
        for (int m = 0; m < 16; ++m) {
            float cv0 = readlane_f(Tr[m], q0 + 0);
            float cv1 = readlane_f(Tr[m], q0 + 1);
            float cv2 = readlane_f(Tr[m], q0 + 2);
            float cv3 = readlane_f(Tr[m], q0 + 3);
            float g = Tr[m] - (cv0 * nr[0] + cv1 * nr[1] + cv2 * nr[2] + cv3 * nr[3]);
            bool rowin = (((w4 * 16 + m) >> 2) == r);
            float gcol = -(cv0 * Bc[0] + cv1 * Bc[1] + cv2 * Bc[2] + cv3 * Bc[3]);
            if (rowin) g = nr[m & 3];
            if (colin) g = rowin ? Bc[m & 3] : gcol;
            Tr[m] = g;
        }
    }
    if (w < 4) {
#pragma unroll
        for (int m = 0; m < 16; ++m) T[(w4 * 16 + m) * 66 + jl] = Tr[m];
    }
    __syncthreads();

    // phase 2: col-half tile update. thread: 2 rows x 2 cols of 64x32
    int tx16 = tid & 15, ty32 = tid >> 4;     // ty32 0..31
    int cb0 = jh * 32;
    if (isdiag) {
#pragma unroll
        for (int m = 0; m < 4; ++m) {
            int idx = tid + 512 * m;
            int i = idx >> 5, j = idx & 31;
            float v = T[i * 66 + cb0 + j];
            Akk[i * DF + cb0 + j] = v;
            if (wbf) pb[(size_t)(k * 64 + i) * DF + k * 64 + cb0 + j] = f2bf(v);
        }
    } else if (isrow) {
        float acc[2][2] = {{0.f}};
#pragma unroll 8
        for (int kk = 0; kk < 64; ++kk) {
            float av0 = T[(ty32 * 2 + 0) * 66 + kk];
            float av1 = T[(ty32 * 2 + 1) * 66 + kk];
            float2 bv = *(const float2*)&LU[kk * 34 + tx16 * 2];
            acc[0][0] += av0 * bv.x; acc[0][1] += av0 * bv.y;
            acc[1][0] += av1 * bv.x; acc[1][1] += av1 * bv.y;
        }
        float* dst = Mb + (k * 64) * DF + tj * 64 + cb0;
#pragma unroll
        for (int r = 0; r < 2; ++r) {
            *(float2*)&dst[(ty32 * 2 + r) * DF + tx16 * 2] = make_float2(acc[r][0], acc[r][1]);
            if (wbf) {
                unsigned up = (unsigned)f2bf(acc[r][0]) | ((unsigned)f2bf(acc[r][1]) << 16);
                *(unsigned*)&pb[(size_t)(k * 64 + ty32 * 2 + r) * DF + tj * 64 + cb0 + tx16 * 2] = up;
            }
        }
    } else if (iscol) {
        float acc[2][2] = {{0.f}};
#pragma unroll 8
        for (int kk = 0; kk < 64; ++kk) {
            float av0 = LV[(ty32 * 2 + 0) * 65 + kk];
            float av1 = LV[(ty32 * 2 + 1) * 65 + kk];
            float2 bv = *(const float2*)&T[kk * 66 + cb0 + tx16 * 2];
            acc[0][0] += av0 * bv.x; acc[0][1] += av0 * bv.y;
            acc[1][0] += av1 * bv.x; acc[1][1] += av1 * bv.y;
        }
        float* dst = Mb + (ti * 64) * DF + k * 64 + cb0;
#pragma unroll
        for (int r = 0; r < 2; ++r) {
            float v0 = -acc[r][0], v1 = -acc[r][1];
            *(float2*)&dst[(ty32 * 2 + r) * DF + tx16 * 2] = make_float2(v0, v1);
            if (wbf) {
                unsigned up = (unsigned)f2bf(v0) | ((unsigned)f2bf(v1) << 16);
                *(unsigned*)&pb[(size_t)(ti * 64 + ty32 * 2 + r) * DF + k * 64 + cb0 + tx16 * 2] = up;
            }
        }
    } else {
        // D1 = P * U_half  (64x32)
        float a1[2][2] = {{0.f}};
#pragma unroll 8
        for (int kk = 0; kk < 64; ++kk) {
            float av0 = T[(ty32 * 2 + 0) * 66 + kk];
            float av1 = T[(ty32 * 2 + 1) * 66 + kk];
            float2 bv = *(const float2*)&LU[kk * 34 + tx16 * 2];
            a1[0][0] += av0 * bv.x; a1[0][1] += av0 * bv.y;
            a1[1][0] += av1 * bv.x; a1[1][1] += av1 * bv.y;
        }
        __syncthreads();
#pragma unroll
        for (int r = 0; r < 2; ++r)
            *(float2*)&D1[(ty32 * 2 + r) * 34 + tx16 * 2] = make_float2(a1[r][0], a1[r][1]);
        __syncthreads();
        // Y_half -= V * D1
        float a2[2][2] = {{0.f}};
#pragma unroll 8
        for (int kk = 0; kk < 64; ++kk) {
            float av0 = LV[(ty32 * 2 + 0) * 65 + kk];
            float av1 = LV[(ty32 * 2 + 1) * 65 + kk];
            float2 bv = *(const float2*)&D1[kk * 34 + tx16 * 2];
            a2[0][0] += av0 * bv.x; a2[0][1] += av0 * bv.y;
            a2[1][0] += av1 * bv.x; a2[1][1] += av1 * bv.y;
        }
        float* dst = Mb + (ti * 64) * DF + tj * 64 + cb0;
#pragma unroll
        for (int r = 0; r < 2; ++r) {
            float2 old = *(const float2*)&dst[(ty32 * 2 + r) * DF + tx16 * 2];
            float nv0 = old.x - a2[r][0], nv1 = old.y - a2[r][1];
            *(float2*)&dst[(ty32 * 2 + r) * DF + tx16 * 2] = make_float2(nv0, nv1);
            if (wbf) {
                unsigned up = (unsigned)f2bf(nv0) | ((unsigned)f2bf(nv1) << 16);
                *(unsigned*)&pb[(size_t)(ti * 64 + ty32 * 2 + r) * DF + tj * 64 + cb0 + tx16 * 2] = up;
            }
        }
    }
}

// ---------------- K4: v_c = P_c m_c, k_c = m^T v ----------------
__global__ __launch_bounds__(256) void k_vk(float* __restrict__ ws) {
    int c = blockIdx.x >> 3, rb = blockIdx.x & 7;
    const float* P = ws + WS_M + c * DF * DF;
    const float* mc = ws + (c ? WS_MEAN1 : WS_MEAN0);
    float* v = ws + (c ? WS_V1 : WS_V0);
    __shared__ float ml[DF];
    __shared__ float red[4][64];
    int tid = threadIdx.x;
    for (int l = tid; l < DF; l += 256) ml[l] = mc[l];
    __syncthreads();
    int rl = tid & 63, ch = tid >> 6;
    int row = rb * 64 + rl;
    float dot = 0.f;
    const float* pr = P + (size_t)row * DF + ch * 128;
    for (int t = 0; t < 32; ++t) {
        float4 pv = *(const float4*)(pr + t * 4);
        const float* mm = ml + ch * 128 + t * 4;
        dot += pv.x * mm[0] + pv.y * mm[1] + pv.z * mm[2] + pv.w * mm[3];
    }
    red[ch][rl] = dot;
    __syncthreads();
    if (ch == 0) {
        float d = red[0][rl] + red[1][rl] + red[2][rl] + red[3][rl];
        v[row] = d;
        float kp = d * ml[row];
#pragma unroll
        for (int off = 32; off > 0; off >>= 1) kp += __shfl_down(kp, off);
        if (rl == 0) atomicAdd(&ws[WS_KC + c], kp);
    }
}

// ---------------- K5: fused Q->bf16 + logits init ----------------
__global__ __launch_bounds__(256) void k_qinit(const float* __restrict__ Q,
                                               float* __restrict__ ws,
                                               float* __restrict__ out) {
    unsigned short* qbw = (unsigned short*)(ws + WS_QB);
    const float* v0 = ws + WS_V0;
    const float* v1 = ws + WS_V1;
    int lane = threadIdx.x & 63;
    int q = blockIdx.x * 4 + (threadIdx.x >> 6);
    const float* qrow = Q + (size_t)q * DF + lane * 8;
    float4 x0 = *(const float4*)(qrow);
    float4 x1 = *(const float4*)(qrow + 4);
    const float* v0p = v0 + lane * 8;
    const float* v1p = v1 + lane * 8;
    float4 w00 = *(const float4*)(v0p), w01 = *(const float4*)(v0p + 4);
    float4 w10 = *(const float4*)(v1p), w11 = *(const float4*)(v1p + 4);
    float a0 = x0.x * w00.x + x0.y * w00.y + x0.z * w00.z + x0.w * w00.w
             + x1.x * w01.x + x1.y * w01.y + x1.z * w01.z + x1.w * w01.w;
    float a1 = x0.x * w10.x + x0.y * w10.y + x0.z * w10.z + x0.w * w10.w
             + x1.x * w11.x + x1.y * w11.y + x1.z * w11.z + x1.w * w11.w;
    short8 r;
    r[0] = (short)f2bf(x0.x); r[1] = (short)f2bf(x0.y);
    r[2] = (short)f2bf(x0.z); r[3] = (short)f2bf(x0.w);
    r[4] = (short)f2bf(x1.x); r[5] = (short)f2bf(x1.y);
    r[6] = (short)f2bf(x1.z); r[7] = (short)f2bf(x1.w);
    *(short8*)(qbw + (size_t)q * DF + lane * 8) = r;
#pragma unroll
    for (int off = 32; off > 0; off >>= 1) {
        a0 += __shfl_down(a0, off);
        a1 += __shfl_down(a1, off);
    }
    if (lane == 0) {
        out[q * 2 + 0] = 2.f * a0 - ws[WS_KC + 0];
        out[q * 2 + 1] = 2.f * a1 - ws[WS_KC + 1];
    }
}

// ---------------- K6: MFMA GEMM, 128x128 tile, LDS staging + swizzle ----------------
__global__ __launch_bounds__(256, 3) void k_gemm(const float* __restrict__ ws,
                                                 float* __restrict__ out) {
    const unsigned short* qb = (const unsigned short*)(ws + WS_QB);
    int c = blockIdx.y >> 2;
    int n0 = (blockIdx.y & 3) * 128;
    const unsigned short* pbc = (const unsigned short*)(ws + WS_PB) + (size_t)c * DF * DF;
    int q0 = blockIdx.x * 128;
    __shared__ __align__(16) unsigned short Abuf[128 * 64];   // 16 KB
    __shared__ __align__(16) unsigned short Bbuf[128 * 64];   // 16 KB
    int tid = threadIdx.x;
    int w = tid >> 6, lane = tid & 63;
    int quad = lane >> 4, l15 = lane & 15;
    floatx4 acc[2][8];
#pragma unroll
    for (int mt = 0; mt < 2; ++mt)
#pragma unroll
        for (int nt = 0; nt < 8; ++nt) acc[mt][nt] = (floatx4)(0.f);

    for (int kt = 0; kt < 8; ++kt) {
        int kc = kt * 64;
        // stage A (128 rows x 64 k): 4 issues of 256 lanes x 16B
#pragma unroll
        for (int i = 0; i < 4; ++i) {
            int o = tid * 16 + i * 4096;
            int row = o >> 7;
            int sg = ((o >> 4) & 7) ^ (row & 7);
            load_lds16(qb + (size_t)(q0 + row) * DF + kc + sg * 8, (char*)Abuf + o);
        }
        // stage B (128 rows x 64 k): 4 issues
#pragma unroll
        for (int i = 0; i < 4; ++i) {
            int o = tid * 16 + i * 4096;
            int row = o >> 7;
            int sg = ((o >> 4) & 7) ^ (row & 7);
            load_lds16(pbc + (size_t)(n0 + row) * DF + kc + sg * 8, (char*)Bbuf + o);
        }
        __syncthreads();
#pragma unroll
        for (int kk2 = 0; kk2 < 2; ++kk2) {
            int u = ((kk2 * 4 + quad) ^ (l15 & 7)) << 4;   // swizzled 16B seg offset
            short8 b[8];
#pragma unroll
            for (int nt = 0; nt < 8; ++nt)
                b[nt] = *(const short8*)((const char*)Bbuf + (nt * 16 + l15) * 128 + u);
#pragma unroll
            for (int mt = 0; mt < 2; ++mt) {
                short8 a = *(const short8*)((const char*)Abuf + (w * 32 + mt * 16 + l15) * 128 + u);
#pragma unroll
                for (int nt = 0; nt < 8; ++nt)
                    acc[mt][nt] = __builtin_amdgcn_mfma_f32_16x16x32_bf16(a, b[nt], acc[mt][nt], 0, 0, 0);
            }
        }
        __syncthreads();
    }
    // epilogue: partial row-dot with Q over this 128-col tile
#pragma unroll
    for (int mt = 0; mt < 2; ++mt)
#pragma unroll
        for (int reg = 0; reg < 4; ++reg) {
            int row = w * 32 + mt * 16 + quad * 4 + reg;
            float part = 0.f;
#pragma unroll
            for (int nt = 0; nt < 8; ++nt) {
                float h = acc[mt][nt][reg];
                unsigned qu = qb[(size_t)(q0 + row) * DF + n0 + nt * 16 + l15];
                part += h * __uint_as_float(qu << 16);
            }
            part += __shfl_xor(part, 1);
            part += __shfl_xor(part, 2);
            part += __shfl_xor(part, 4);
            part += __shfl_xor(part, 8);
            if (l15 == 0) atomicAdd(&out[(size_t)(q0 + row) * 2 + c], -part);
        }
}

extern "C" void kernel_launch(void* const* d_in, const int* in_sizes, int n_in,
                              void* d_out, int out_size, void* d_ws, size_t ws_size,
                              hipStream_t stream) {
    const float* S = (const float*)d_in[0];
    const int* lab = (const int*)d_in[1];
    const float* Q = (const float*)d_in[2];
    float* out = (float*)d_out;
    float* ws = (float*)d_ws;

    k_stats<<<8, 512, 0, stream>>>(S, lab, ws);
    k_gram_part<<<dim3(8, 8, 8), dim3(16, 16), 0, stream>>>(S, lab, ws);
    k_asm<<<1024, 256, 0, stream>>>(ws);
    for (int k = 0; k < 8; ++k)
        k_step<<<dim3(64, 2, 2), 512, 0, stream>>>(ws, k, k == 7 ? 1 : 0);
    k_vk<<<16, 256, 0, stream>>>(ws);
    k_qinit<<<NQ / 4, 256, 0, stream>>>(Q, ws, out);
    k_gemm<<<dim3(NQ / 128, 8), 256, 0, stream>>>(ws, out);
}

// Round 5
// 353.251 us; speedup vs baseline: 1.8764x; 1.0968x over previous
//
#include <hip/hip_runtime.h>

#define NS 512
#define DF 512
#define NQ 16384

// ws layout (float offsets)
#define WS_MEAN0 0
#define WS_MEAN1 512
#define WS_MEANA 1024
#define WS_CNT   1536
#define WS_V0    2048
#define WS_V1    2560
#define WS_KC    3072
#define WS_M     4096                      // M / P fp32 [2][512][512]
#define WS_PB    (WS_M + 2*DF*DF)          // P bf16 [2][512][512] (as ushort)
#define WS_QB    (WS_PB + DF*DF)           // Q bf16 [16384][512] (ushort); ALSO Gram partials earlier
#define WS_GP    WS_QB                     // Gp [8 chunks][2 cls][512][512] f32 (dead after k_asm)
#define WS_SCR   WS_QB                     // T-hat scratch [par][c][4096] aliases dead Gp head
                                           // (dead before k_qinit overwrites QB rows 0..63)

typedef __attribute__((ext_vector_type(8))) short short8;
typedef __attribute__((ext_vector_type(4))) float floatx4;

__device__ __forceinline__ unsigned short f2bf(float f) {
    unsigned u = __float_as_uint(f);
    unsigned r = (u + 0x7fffu + ((u >> 16) & 1u)) >> 16;
    return (unsigned short)r;
}

// readlane for float: raw builtin takes i32 -> bitcast explicitly (R5 bug).
__device__ __forceinline__ float readlane_f(float v, int lane) {
    return __uint_as_float(__builtin_amdgcn_readlane(__float_as_uint(v), lane));
}

__device__ __forceinline__ void load_lds16(const void* g, void* l) {
    __builtin_amdgcn_global_load_lds(
        (const __attribute__((address_space(1))) unsigned int*)g,
        (__attribute__((address_space(3))) unsigned int*)l, 16, 0, 0);
}

// -------- shared: 64x64 SPD Gauss-Jordan inversion of LDS T (stride 66) --------
// 16 rounds of 4 pivots. Waves 0..3 own 16 rows each; waves >=4 idle through
// the barriers. All threads of the block MUST call.
__device__ __forceinline__ void gj_invert64(float* T, float (*rbuf)[4][64], int tid) {
    int jl = tid & 63, w = tid >> 6;
    float Tr[16];
    if (w < 4) {
#pragma unroll
        for (int m = 0; m < 16; ++m) Tr[m] = T[(w * 16 + m) * 66 + jl];
    }
#pragma unroll
    for (int r = 0; r < 16; ++r) {
        const int q0 = r * 4;
        const int par = r & 1;
        if (w == (q0 >> 4)) {               // only a wave in 0..3 matches
            const int mb = q0 & 15;
            rbuf[par][0][jl] = Tr[mb + 0];
            rbuf[par][1][jl] = Tr[mb + 1];
            rbuf[par][2][jl] = Tr[mb + 2];
            rbuf[par][3][jl] = Tr[mb + 3];
        }
        __syncthreads();
        if (w < 4) {
            float B[4][4];
#pragma unroll
            for (int a = 0; a < 4; ++a)
#pragma unroll
                for (int bb = 0; bb < 4; ++bb) B[a][bb] = rbuf[par][a][q0 + bb];
            // invert B in place (GJ, no pivoting: SPD principal block)
#pragma unroll
            for (int p = 0; p < 4; ++p) {
                float piv = 1.0f / B[p][p];
#pragma unroll
                for (int j = 0; j < 4; ++j) if (j != p) B[p][j] *= piv;
#pragma unroll
                for (int i = 0; i < 4; ++i) if (i != p) {
                    float f = B[i][p];
#pragma unroll
                    for (int j = 0; j < 4; ++j) if (j != p) B[i][j] -= f * B[p][j];
                    B[i][p] = -f * piv;
                }
                B[p][p] = piv;
            }
            float r0v = rbuf[par][0][jl], r1v = rbuf[par][1][jl];
            float r2v = rbuf[par][2][jl], r3v = rbuf[par][3][jl];
            float nr[4];
#pragma unroll
            for (int a = 0; a < 4; ++a)
                nr[a] = B[a][0] * r0v + B[a][1] * r1v + B[a][2] * r2v + B[a][3] * r3v;
            bool colin = ((jl >> 2) == r);
            int bsel = jl & 3;
            float Bc[4];
#pragma unroll
            for (int a = 0; a < 4; ++a)
                Bc[a] = bsel == 0 ? B[a][0]
                      : (bsel == 1 ? B[a][1] : (bsel == 2 ? B[a][2] : B[a][3]));
#pragma unroll
            for (int m = 0; m < 16; ++m) {
                float cv0 = readlane_f(Tr[m], q0 + 0);
                float cv1 = readlane_f(Tr[m], q0 + 1);
                float cv2 = readlane_f(Tr[m], q0 + 2);
                float cv3 = readlane_f(Tr[m], q0 + 3);
                float g = Tr[m] - (cv0 * nr[0] + cv1 * nr[1] + cv2 * nr[2] + cv3 * nr[3]);
                bool rowin = (((w * 16 + m) >> 2) == r);
                float gcol = -(cv0 * Bc[0] + cv1 * Bc[1] + cv2 * Bc[2] + cv3 * Bc[3]);
                if (rowin) g = nr[m & 3];
                if (colin) g = rowin ? Bc[m & 3] : gcol;
                Tr[m] = g;
            }
        }
    }
    if (w < 4) {
#pragma unroll
        for (int m = 0; m < 16; ++m) T[(w * 16 + m) * 66 + jl] = Tr[m];
    }
    __syncthreads();
}

// ---------------- K1: fused stats (blocks 512..519) + masked Grams (0..511) ----------------
__global__ __launch_bounds__(256) void k_front(const float* __restrict__ S,
                                               const int* __restrict__ lab,
                                               float* __restrict__ ws) {
    int b = blockIdx.x, tid = threadIdx.x;
    if (b >= 512) {
        __shared__ int slb[NS];
        __shared__ float r0[4][64], r1[4][64];
        __shared__ int rc[4];
        int bs = b - 512;
        for (int l = tid; l < NS; l += 256) slb[l] = lab[l];
        __syncthreads();
        int dl = tid & 63, ch = tid >> 6;          // ch 0..3
        int dd = bs * 64 + dl;
        float s0 = 0.f, s1 = 0.f;
        int n1 = 0;
        for (int n = ch * 128; n < ch * 128 + 128; ++n) {
            float v = S[n * DF + dd];
            if (slb[n]) { s1 += v; n1++; } else { s0 += v; }
        }
        r0[ch][dl] = s0; r1[ch][dl] = s1;
        if (dl == 0) rc[ch] = n1;
        __syncthreads();
        if (ch == 0) {
            float t0 = 0.f, t1 = 0.f; int n1t = 0;
#pragma unroll
            for (int x = 0; x < 4; ++x) { t0 += r0[x][dl]; t1 += r1[x][dl]; n1t += rc[x]; }
            float fn1 = (float)n1t, fn0 = (float)(NS - n1t);
            ws[WS_MEAN0 + dd] = t0 / fn0;
            ws[WS_MEAN1 + dd] = t1 / fn1;
            ws[WS_MEANA + dd] = (t0 + t1) / (float)NS;
            if (bs == 0 && dl == 0) {
                ws[WS_CNT] = fn0; ws[WS_CNT + 1] = fn1;
                ws[WS_KC] = 0.f; ws[WS_KC + 1] = 0.f;
            }
        }
        return;
    }
    __shared__ float SA[16 * 65];
    __shared__ float SB[16 * 65];
    __shared__ int lb[16];
    int tx = tid & 15, ty = tid >> 4;
    int i0 = (b & 7) * 64, j0 = ((b >> 3) & 7) * 64;
    int z = b >> 6;
    float a0[4][4] = {{0.f}}, a1[4][4] = {{0.f}};
    for (int nc = z * 64; nc < z * 64 + 64; nc += 16) {
#pragma unroll
        for (int l = 0; l < 4; ++l) {
            int idx = tid + 256 * l;
            int nn = idx >> 6, col = idx & 63;
            SA[nn * 65 + col] = S[(nc + nn) * DF + i0 + col];
            SB[nn * 65 + col] = S[(nc + nn) * DF + j0 + col];
        }
        if (tid < 16) lb[tid] = lab[nc + tid];
        __syncthreads();
#pragma unroll
        for (int kk = 0; kk < 16; ++kk) {
            float av[4], bv[4];
#pragma unroll
            for (int r = 0; r < 4; ++r) av[r] = SA[kk * 65 + ty * 4 + r];
#pragma unroll
            for (int s = 0; s < 4; ++s) bv[s] = SB[kk * 65 + tx * 4 + s];
            if (lb[kk]) {
#pragma unroll
                for (int r = 0; r < 4; ++r)
#pragma unroll
                    for (int s = 0; s < 4; ++s) a1[r][s] += av[r] * bv[s];
            } else {
#pragma unroll
                for (int r = 0; r < 4; ++r)
#pragma unroll
                    for (int s = 0; s < 4; ++s) a0[r][s] += av[r] * bv[s];
            }
        }
        __syncthreads();
    }
    float* Gp = ws + WS_GP;
#pragma unroll
    for (int r = 0; r < 4; ++r) {
        int i = i0 + ty * 4 + r;
#pragma unroll
        for (int s = 0; s < 4; ++s) {
            int j = j0 + tx * 4 + s;
            Gp[((z * 2 + 0) * DF + i) * DF + j] = a0[r][s];
            Gp[((z * 2 + 1) * DF + i) * DF + j] = a1[r][s];
        }
    }
}

// ---------------- K2b: assemble M_c from partials ----------------
__global__ __launch_bounds__(256) void k_asm(float* __restrict__ ws) {
    const float* Gp = ws + WS_GP;
    int e = blockIdx.x * 256 + threadIdx.x;   // 0..262143
    int i = e >> 9, j = e & 511;
    float g0 = 0.f, g1 = 0.f;
#pragma unroll
    for (int ch = 0; ch < 8; ++ch) {
        g0 += Gp[((ch * 2 + 0) * DF + i) * DF + j];
        g1 += Gp[((ch * 2 + 1) * DF + i) * DF + j];
    }
    float n0 = ws[WS_CNT], n1 = ws[WS_CNT + 1];
    float lam0 = fminf(n0 / (n0 + 1.f), 0.1f);
    float lam1 = fminf(n1 / (n1 + 1.f), 0.1f);
    float m0i = ws[WS_MEAN0 + i], m1i = ws[WS_MEAN1 + i], mai = ws[WS_MEANA + i];
    float m0j = ws[WS_MEAN0 + j], m1j = ws[WS_MEAN1 + j], maj = ws[WS_MEANA + j];
    float task = (g0 + g1 - (float)NS * mai * maj) / (float)(NS - 1);
    float cov0 = (g0 - n0 * m0i * m0j) / (n0 - 1.f);
    float cov1 = (g1 - n1 * m1i * m1j) / (n1 - 1.f);
    float dg = (i == j) ? 0.1f : 0.f;
    ws[WS_M + i * DF + j] = lam0 * cov0 + (1.f - lam0) * task + dg;
    ws[WS_M + DF * DF + i * DF + j] = lam1 * cov1 + (1.f - lam1) * task + dg;
}

// ---------------- K3a: invert M[0][0] once per class -> SCR[par=0] ----------------
__global__ __launch_bounds__(256) void k_pivot0(float* __restrict__ ws) {
    int c = blockIdx.x;
    __shared__ float T[64 * 66];
    __shared__ float rbuf[2][4][64];
    const float* Akk = ws + WS_M + (size_t)c * DF * DF;
    int tid = threadIdx.x;
#pragma unroll
    for (int m = 0; m < 16; ++m) {
        int idx = tid + 256 * m;
        int i = idx >> 6, j = idx & 63;
        T[i * 66 + j] = Akk[i * DF + j];
    }
    __syncthreads();
    gj_invert64(T, rbuf, tid);
    float* scr = ws + WS_SCR + (0 * 2 + c) * 4096;
#pragma unroll
    for (int m = 0; m < 16; ++m) {
        int idx = tid + 256 * m;
        int i = idx >> 6, j = idx & 63;
        scr[i * 64 + j] = T[i * 66 + j];
    }
}

// ---------------- K3b-A: trailing update (reads row/col k; writes trailing only) ----------------
// Y[ti][tj] -= V * (T-hat_k * U),  V = M[ti][k], U = M[k][tj] (old values,
// untouched within this launch). T-hat_k from SCR. Race-free: no block here
// writes anything another block in this launch reads.
__global__ __launch_bounds__(512) void k_updA(float* __restrict__ ws, int k, int wbf) {
    int c = blockIdx.y, jh = blockIdx.z;
    int ti = blockIdx.x >> 3, tj = blockIdx.x & 7;
    if (ti == k || tj == k) return;
    float* Mb = ws + WS_M + (size_t)c * DF * DF;
    unsigned short* pb = (unsigned short*)(ws + WS_PB) + (size_t)c * DF * DF;
    const float* scr_in = ws + WS_SCR + ((k & 1) * 2 + c) * 4096;
    int tid = threadIdx.x;
    __shared__ float T[64 * 66];
    __shared__ float LV[64 * 65];
    __shared__ float LU[64 * 34];
    __shared__ float D1[64 * 34];
#pragma unroll
    for (int m = 0; m < 8; ++m) {
        int idx = tid + 512 * m;
        int i = idx >> 6, j = idx & 63;
        T[i * 66 + j] = scr_in[i * 64 + j];
    }
    {
        const float* src = Mb + (ti * 64) * DF + k * 64;   // V full
#pragma unroll
        for (int m = 0; m < 8; ++m) {
            int idx = tid + 512 * m;
            int i = idx >> 6, j = idx & 63;
            LV[i * 65 + j] = src[i * DF + j];
        }
    }
    {
        const float* src = Mb + (k * 64) * DF + tj * 64 + jh * 32;   // U half
#pragma unroll
        for (int m = 0; m < 4; ++m) {
            int idx = tid + 512 * m;
            int i = idx >> 5, j = idx & 31;
            LU[i * 34 + j] = src[i * DF + j];
        }
    }
    __syncthreads();
    int tx16 = tid & 15, ty32 = tid >> 4;
    int cb0 = jh * 32;
    float a1[2][2] = {{0.f}};
#pragma unroll 8
    for (int kk = 0; kk < 64; ++kk) {
        float av0 = T[(ty32 * 2 + 0) * 66 + kk];
        float av1 = T[(ty32 * 2 + 1) * 66 + kk];
        float2 bv = *(const float2*)&LU[kk * 34 + tx16 * 2];
        a1[0][0] += av0 * bv.x; a1[0][1] += av0 * bv.y;
        a1[1][0] += av1 * bv.x; a1[1][1] += av1 * bv.y;
    }
#pragma unroll
    for (int r = 0; r < 2; ++r)
        *(float2*)&D1[(ty32 * 2 + r) * 34 + tx16 * 2] = make_float2(a1[r][0], a1[r][1]);
    __syncthreads();
    float a2[2][2] = {{0.f}};
#pragma unroll 8
    for (int kk = 0; kk < 64; ++kk) {
        float av0 = LV[(ty32 * 2 + 0) * 65 + kk];
        float av1 = LV[(ty32 * 2 + 1) * 65 + kk];
        float2 bv = *(const float2*)&D1[kk * 34 + tx16 * 2];
        a2[0][0] += av0 * bv.x; a2[0][1] += av0 * bv.y;
        a2[1][0] += av1 * bv.x; a2[1][1] += av1 * bv.y;
    }
    float* dst = Mb + (ti * 64) * DF + tj * 64 + cb0;
#pragma unroll
    for (int r = 0; r < 2; ++r) {
        float2 old = *(const float2*)&dst[(ty32 * 2 + r) * DF + tx16 * 2];
        float nv0 = old.x - a2[r][0], nv1 = old.y - a2[r][1];
        *(float2*)&dst[(ty32 * 2 + r) * DF + tx16 * 2] = make_float2(nv0, nv1);
        if (wbf) {
            unsigned up = (unsigned)f2bf(nv0) | ((unsigned)f2bf(nv1) << 16);
            *(unsigned*)&pb[(size_t)(ti * 64 + ty32 * 2 + r) * DF + tj * 64 + cb0 + tx16 * 2] = up;
        }
    }
}

// ---------------- K3b-B: row/col/diag updates + next-pivot inversion ----------------
// x<8: row tiles, jh halves (x==k -> diag copy). 8<=x<16: col tiles, FULL
// 64x64 per block (jh==1 twin idles -- a col block must read the whole old V
// while writing the tile, so splitting it across two blocks would race).
// x==16: invert updated M[k+1][k+1] (written by k_updA this step) -> SCR.
__global__ __launch_bounds__(512) void k_updB(float* __restrict__ ws, int k, int wbf) {
    int c = blockIdx.y, jh = blockIdx.z;
    int x = blockIdx.x;
    int tid = threadIdx.x;
    __shared__ float T[64 * 66];
    __shared__ float X[64 * 65];
    float* Mb = ws + WS_M + (size_t)c * DF * DF;
    unsigned short* pb = (unsigned short*)(ws + WS_PB) + (size_t)c * DF * DF;
    const float* scr_in = ws + WS_SCR + ((k & 1) * 2 + c) * 4096;

    if (x == 16) {
        if (jh == 1 || k == 7) return;
        const float* src = Mb + ((k + 1) * 64) * DF + (k + 1) * 64;
#pragma unroll
        for (int m = 0; m < 8; ++m) {
            int idx = tid + 512 * m;
            int i = idx >> 6, j = idx & 63;
            T[i * 66 + j] = src[i * DF + j];
        }
        __syncthreads();
        gj_invert64(T, (float(*)[4][64])X, tid);
        float* scr_out = ws + WS_SCR + (((k + 1) & 1) * 2 + c) * 4096;
#pragma unroll
        for (int m = 0; m < 8; ++m) {
            int idx = tid + 512 * m;
            int i = idx >> 6, j = idx & 63;
            scr_out[i * 64 + j] = T[i * 66 + j];
        }
        return;
    }
    int cb0 = jh * 32;
    int tx16 = tid & 15, ty32 = tid >> 4;
    if (x < 8) {
        int tj = x;
        if (tj == k) {
            // diag: M[k][k] = T-hat_k (half jh)
            float* Akk = Mb + (k * 64) * DF + k * 64;
#pragma unroll
            for (int m = 0; m < 4; ++m) {
                int idx = tid + 512 * m;
                int i = idx >> 5, j = idx & 31;
                float v = scr_in[i * 64 + cb0 + j];
                Akk[i * DF + cb0 + j] = v;
                if (wbf) pb[(size_t)(k * 64 + i) * DF + k * 64 + cb0 + j] = f2bf(v);
            }
            return;
        }
        // row: M[k][tj] = T-hat * U_old (reads own half, writes own half)
#pragma unroll
        for (int m = 0; m < 8; ++m) {
            int idx = tid + 512 * m;
            int i = idx >> 6, j = idx & 63;
            T[i * 66 + j] = scr_in[i * 64 + j];
        }
        {
            const float* src = Mb + (k * 64) * DF + tj * 64 + cb0;   // U half
#pragma unroll
            for (int m = 0; m < 4; ++m) {
                int idx = tid + 512 * m;
                int i = idx >> 5, j = idx & 31;
                X[i * 34 + j] = src[i * DF + j];    // packed stride 34
            }
        }
        __syncthreads();
        float acc[2][2] = {{0.f}};
#pragma unroll 8
        for (int kk = 0; kk < 64; ++kk) {
            float av0 = T[(ty32 * 2 + 0) * 66 + kk];
            float av1 = T[(ty32 * 2 + 1) * 66 + kk];
            float2 bv = *(const float2*)&X[kk * 34 + tx16 * 2];
            acc[0][0] += av0 * bv.x; acc[0][1] += av0 * bv.y;
            acc[1][0] += av1 * bv.x; acc[1][1] += av1 * bv.y;
        }
        float* dst = Mb + (k * 64) * DF + tj * 64 + cb0;
#pragma unroll
        for (int r = 0; r < 2; ++r) {
            *(float2*)&dst[(ty32 * 2 + r) * DF + tx16 * 2] = make_float2(acc[r][0], acc[r][1]);
            if (wbf) {
                unsigned up = (unsigned)f2bf(acc[r][0]) | ((unsigned)f2bf(acc[r][1]) << 16);
                *(unsigned*)&pb[(size_t)(k * 64 + ty32 * 2 + r) * DF + tj * 64 + cb0 + tx16 * 2] = up;
            }
        }
    } else {
        int ti = x - 8;
        if (ti == k || jh == 1) return;
        // col: M[ti][k] = -V_old * T-hat, FULL tile in one block
#pragma unroll
        for (int m = 0; m < 8; ++m) {
            int idx = tid + 512 * m;
            int i = idx >> 6, j = idx & 63;
            T[i * 66 + j] = scr_in[i * 64 + j];
        }
        {
            const float* src = Mb + (ti * 64) * DF + k * 64;   // V full
#pragma unroll
            for (int m = 0; m < 8; ++m) {
                int idx = tid + 512 * m;
                int i = idx >> 6, j = idx & 63;
                X[i * 65 + j] = src[i * DF + j];
            }
        }
        __syncthreads();
        float acc[2][2][2];   // [pass][r][s]
#pragma unroll
        for (int p = 0; p < 2; ++p)
#pragma unroll
            for (int r = 0; r < 2; ++r) { acc[p][r][0] = 0.f; acc[p][r][1] = 0.f; }
#pragma unroll 4
        for (int kk = 0; kk < 64; ++kk) {
            float av0 = X[(ty32 * 2 + 0) * 65 + kk];
            float av1 = X[(ty32 * 2 + 1) * 65 + kk];
            float2 b0 = *(const float2*)&T[kk * 66 + tx16 * 2];
            float2 b1 = *(const float2*)&T[kk * 66 + 32 + tx16 * 2];
            acc[0][0][0] += av0 * b0.x; acc[0][0][1] += av0 * b0.y;
            acc[0][1][0] += av1 * b0.x; acc[0][1][1] += av1 * b0.y;
            acc[1][0][0] += av0 * b1.x; acc[1][0][1] += av0 * b1.y;
            acc[1][1][0] += av1 * b1.x; acc[1][1][1] += av1 * b1.y;
        }
        float* dst = Mb + (ti * 64) * DF + k * 64;
#pragma unroll
        for (int p = 0; p < 2; ++p)
#pragma unroll
            for (int r = 0; r < 2; ++r) {
                int row = ty32 * 2 + r, col = p * 32 + tx16 * 2;
                float v0 = -acc[p][r][0], v1 = -acc[p][r][1];
                *(float2*)&dst[row * DF + col] = make_float2(v0, v1);
                if (wbf) {
                    unsigned up = (unsigned)f2bf(v0) | ((unsigned)f2bf(v1) << 16);
                    *(unsigned*)&pb[(size_t)(ti * 64 + row) * DF + k * 64 + col] = up;
                }
            }
    }
}

// ---------------- K4: v_c = P_c m_c, k_c = m^T v ----------------
__global__ __launch_bounds__(256) void k_vk(float* __restrict__ ws) {
    int c = blockIdx.x >> 3, rb = blockIdx.x & 7;
    const float* P = ws + WS_M + (size_t)c * DF * DF;
    const float* mc = ws + (c ? WS_MEAN1 : WS_MEAN0);
    float* v = ws + (c ? WS_V1 : WS_V0);
    __shared__ float ml[DF];
    __shared__ float red[4][64];
    int tid = threadIdx.x;
    for (int l = tid; l < DF; l += 256) ml[l] = mc[l];
    __syncthreads();
    int rl = tid & 63, ch = tid >> 6;
    int row = rb * 64 + rl;
    float dot = 0.f;
    const float* pr = P + (size_t)row * DF + ch * 128;
    for (int t = 0; t < 32; ++t) {
        float4 pv = *(const float4*)(pr + t * 4);
        const float* mm = ml + ch * 128 + t * 4;
        dot += pv.x * mm[0] + pv.y * mm[1] + pv.z * mm[2] + pv.w * mm[3];
    }
    red[ch][rl] = dot;
    __syncthreads();
    if (ch == 0) {
        float d = red[0][rl] + red[1][rl] + red[2][rl] + red[3][rl];
        v[row] = d;
        float kp = d * ml[row];
#pragma unroll
        for (int off = 32; off > 0; off >>= 1) kp += __shfl_down(kp, off);
        if (rl == 0) atomicAdd(&ws[WS_KC + c], kp);
    }
}

// ---------------- K5: fused Q->bf16 + logits init ----------------
__global__ __launch_bounds__(256) void k_qinit(const float* __restrict__ Q,
                                               float* __restrict__ ws,
                                               float* __restrict__ out) {
    unsigned short* qbw = (unsigned short*)(ws + WS_QB);
    const float* v0 = ws + WS_V0;
    const float* v1 = ws + WS_V1;
    int lane = threadIdx.x & 63;
    int q = blockIdx.x * 4 + (threadIdx.x >> 6);
    const float* qrow = Q + (size_t)q * DF + lane * 8;
    float4 x0 = *(const float4*)(qrow);
    float4 x1 = *(const float4*)(qrow + 4);
    const float* v0p = v0 + lane * 8;
    const float* v1p = v1 + lane * 8;
    float4 w00 = *(const float4*)(v0p), w01 = *(const float4*)(v0p + 4);
    float4 w10 = *(const float4*)(v1p), w11 = *(const float4*)(v1p + 4);
    float a0 = x0.x * w00.x + x0.y * w00.y + x0.z * w00.z + x0.w * w00.w
             + x1.x * w01.x + x1.y * w01.y + x1.z * w01.z + x1.w * w01.w;
    float a1 = x0.x * w10.x + x0.y * w10.y + x0.z * w10.z + x0.w * w10.w
             + x1.x * w11.x + x1.y * w11.y + x1.z * w11.z + x1.w * w11.w;
    short8 r;
    r[0] = (short)f2bf(x0.x); r[1] = (short)f2bf(x0.y);
    r[2] = (short)f2bf(x0.z); r[3] = (short)f2bf(x0.w);
    r[4] = (short)f2bf(x1.x); r[5] = (short)f2bf(x1.y);
    r[6] = (short)f2bf(x1.z); r[7] = (short)f2bf(x1.w);
    *(short8*)(qbw + (size_t)q * DF + lane * 8) = r;
#pragma unroll
    for (int off = 32; off > 0; off >>= 1) {
        a0 += __shfl_down(a0, off);
        a1 += __shfl_down(a1, off);
    }
    if (lane == 0) {
        out[q * 2 + 0] = 2.f * a0 - ws[WS_KC + 0];
        out[q * 2 + 1] = 2.f * a1 - ws[WS_KC + 1];
    }
}

// ---------------- K6: MFMA GEMM, 128x128 tile, LDS staging + swizzle ----------------
__global__ __launch_bounds__(256, 3) void k_gemm(const float* __restrict__ ws,
                                                 float* __restrict__ out) {
    const unsigned short* qb = (const unsigned short*)(ws + WS_QB);
    int c = blockIdx.y >> 2;
    int n0 = (blockIdx.y & 3) * 128;
    const unsigned short* pbc = (const unsigned short*)(ws + WS_PB) + (size_t)c * DF * DF;
    int q0 = blockIdx.x * 128;
    __shared__ __align__(16) unsigned short Abuf[128 * 64];   // 16 KB
    __shared__ __align__(16) unsigned short Bbuf[128 * 64];   // 16 KB
    int tid = threadIdx.x;
    int w = tid >> 6, lane = tid & 63;
    int quad = lane >> 4, l15 = lane & 15;
    floatx4 acc[2][8];
#pragma unroll
    for (int mt = 0; mt < 2; ++mt)
#pragma unroll
        for (int nt = 0; nt < 8; ++nt) acc[mt][nt] = (floatx4)(0.f);

    for (int kt = 0; kt < 8; ++kt) {
        int kc2 = kt * 64;
#pragma unroll
        for (int i = 0; i < 4; ++i) {
            int o = tid * 16 + i * 4096;
            int row = o >> 7;
            int sg = ((o >> 4) & 7) ^ (row & 7);
            load_lds16(qb + (size_t)(q0 + row) * DF + kc2 + sg * 8, (char*)Abuf + o);
        }
#pragma unroll
        for (int i = 0; i < 4; ++i) {
            int o = tid * 16 + i * 4096;
            int row = o >> 7;
            int sg = ((o >> 4) & 7) ^ (row & 7);
            load_lds16(pbc + (size_t)(n0 + row) * DF + kc2 + sg * 8, (char*)Bbuf + o);
        }
        __syncthreads();
#pragma unroll
        for (int kk2 = 0; kk2 < 2; ++kk2) {
            int u = ((kk2 * 4 + quad) ^ (l15 & 7)) << 4;   // swizzled 16B seg offset
            short8 b[8];
#pragma unroll
            for (int nt = 0; nt < 8; ++nt)
                b[nt] = *(const short8*)((const char*)Bbuf + (nt * 16 + l15) * 128 + u);
#pragma unroll
            for (int mt = 0; mt < 2; ++mt) {
                short8 a = *(const short8*)((const char*)Abuf + (w * 32 + mt * 16 + l15) * 128 + u);
#pragma unroll
                for (int nt = 0; nt < 8; ++nt)
                    acc[mt][nt] = __builtin_amdgcn_mfma_f32_16x16x32_bf16(a, b[nt], acc[mt][nt], 0, 0, 0);
            }
        }
        __syncthreads();
    }
    // epilogue: partial row-dot with Q over this 128-col tile
#pragma unroll
    for (int mt = 0; mt < 2; ++mt)
#pragma unroll
        for (int reg = 0; reg < 4; ++reg) {
            int row = w * 32 + mt * 16 + quad * 4 + reg;
            float part = 0.f;
#pragma unroll
            for (int nt = 0; nt < 8; ++nt) {
                float h = acc[mt][nt][reg];
                unsigned qu = qb[(size_t)(q0 + row) * DF + n0 + nt * 16 + l15];
                part += h * __uint_as_float(qu << 16);
            }
            part += __shfl_xor(part, 1);
            part += __shfl_xor(part, 2);
            part += __shfl_xor(part, 4);
            part += __shfl_xor(part, 8);
            if (l15 == 0) atomicAdd(&out[(size_t)(q0 + row) * 2 + c], -part);
        }
}

extern "C" void kernel_launch(void* const* d_in, const int* in_sizes, int n_in,
                              void* d_out, int out_size, void* d_ws, size_t ws_size,
                              hipStream_t stream) {
    const float* S = (const float*)d_in[0];
    const int* lab = (const int*)d_in[1];
    const float* Q = (const float*)d_in[2];
    float* out = (float*)d_out;
    float* ws = (float*)d_ws;

    k_front<<<520, 256, 0, stream>>>(S, lab, ws);
    k_asm<<<1024, 256, 0, stream>>>(ws);
    k_pivot0<<<2, 256, 0, stream>>>(ws);
    for (int k = 0; k < 8; ++k) {
        int wbf = (k == 7) ? 1 : 0;
        k_updA<<<dim3(64, 2, 2), 512, 0, stream>>>(ws, k, wbf);
        k_updB<<<dim3(17, 2, 2), 512, 0, stream>>>(ws, k, wbf);
    }
    k_vk<<<16, 256, 0, stream>>>(ws);
    k_qinit<<<NQ / 4, 256, 0, stream>>>(Q, ws, out);
    k_gemm<<<dim3(NQ / 128, 8), 256, 0, stream>>>(ws, out);
}

// Round 8
// 340.402 us; speedup vs baseline: 1.9472x; 1.0377x over previous
//
#include <hip/hip_runtime.h>

#define NS 512
#define DF 512
#define NQ 16384

// ws layout (float offsets)
#define WS_MEAN0 0
#define WS_MEAN1 512
#define WS_MEANA 1024
#define WS_CNT   1536
#define WS_V0    2048
#define WS_V1    2560
#define WS_KC    3072
#define WS_M     4096                      // M / P fp32 [2][512][512]
#define WS_PB    (WS_M + 2*DF*DF)          // P bf16 [2][512][512] (as ushort) -- written POST-GJ
#define WS_QB    (WS_PB + DF*DF)           // Q bf16 (written by k_qinit)
#define WS_GP    WS_QB                     // Gp [8][2][512][512] f32 (dead after k_asm; QB overwrites later)
// GJ scratch ALIASES the dead PB region (PB only written after the GJ loop).
// UC[par][c][slot][4096]: U copies; slot k doubles as T-hat_k storage at step k.
// VC[par][c][slot][4096]: V copies. Total = 262144 floats = exactly PB's size.
#define WS_UC    WS_PB
#define WS_VC    (WS_PB + 2*2*8*4096)

typedef __attribute__((ext_vector_type(8))) short short8;
typedef __attribute__((ext_vector_type(4))) float floatx4;

__device__ __forceinline__ unsigned short f2bf(float f) {
    unsigned u = __float_as_uint(f);
    unsigned r = (u + 0x7fffu + ((u >> 16) & 1u)) >> 16;
    return (unsigned short)r;
}

// readlane for float: raw builtin takes i32 -> bitcast explicitly (R5 bug).
__device__ __forceinline__ float readlane_f(float v, int lane) {
    return __uint_as_float(__builtin_amdgcn_readlane(__float_as_uint(v), lane));
}

__device__ __forceinline__ void load_lds16(const void* g, void* l) {
    __builtin_amdgcn_global_load_lds(
        (const __attribute__((address_space(1))) unsigned int*)g,
        (__attribute__((address_space(3))) unsigned int*)l, 16, 0, 0);
}

// -------- shared: 64x64 SPD Gauss-Jordan inversion of LDS T (stride 66) --------
// 16 rounds of 4 pivots; 256 threads (4 waves, each owns 16 rows).
__device__ __forceinline__ void gj_invert64(float* T, float (*rbuf)[4][64], int tid) {
    int jl = tid & 63, w = tid >> 6;
    float Tr[16];
#pragma unroll
    for (int m = 0; m < 16; ++m) Tr[m] = T[(w * 16 + m) * 66 + jl];
#pragma unroll
    for (int r = 0; r < 16; ++r) {
        const int q0 = r * 4;
        const int par = r & 1;
        if (w == (q0 >> 4)) {
            const int mb = q0 & 15;
            rbuf[par][0][jl] = Tr[mb + 0];
            rbuf[par][1][jl] = Tr[mb + 1];
            rbuf[par][2][jl] = Tr[mb + 2];
            rbuf[par][3][jl] = Tr[mb + 3];
        }
        __syncthreads();
        float B[4][4];
#pragma unroll
        for (int a = 0; a < 4; ++a)
#pragma unroll
            for (int bb = 0; bb < 4; ++bb) B[a][bb] = rbuf[par][a][q0 + bb];
#pragma unroll
        for (int p = 0; p < 4; ++p) {
            float piv = 1.0f / B[p][p];
#pragma unroll
            for (int j = 0; j < 4; ++j) if (j != p) B[p][j] *= piv;
#pragma unroll
            for (int i = 0; i < 4; ++i) if (i != p) {
                float f = B[i][p];
#pragma unroll
                for (int j = 0; j < 4; ++j) if (j != p) B[i][j] -= f * B[p][j];
                B[i][p] = -f * piv;
            }
            B[p][p] = piv;
        }
        float r0v = rbuf[par][0][jl], r1v = rbuf[par][1][jl];
        float r2v = rbuf[par][2][jl], r3v = rbuf[par][3][jl];
        float nr[4];
#pragma unroll
        for (int a = 0; a < 4; ++a)
            nr[a] = B[a][0] * r0v + B[a][1] * r1v + B[a][2] * r2v + B[a][3] * r3v;
        bool colin = ((jl >> 2) == r);
        int bsel = jl & 3;
        float Bc[4];
#pragma unroll
        for (int a = 0; a < 4; ++a)
            Bc[a] = bsel == 0 ? B[a][0]
                  : (bsel == 1 ? B[a][1] : (bsel == 2 ? B[a][2] : B[a][3]));
#pragma unroll
        for (int m = 0; m < 16; ++m) {
            float cv0 = readlane_f(Tr[m], q0 + 0);
            float cv1 = readlane_f(Tr[m], q0 + 1);
            float cv2 = readlane_f(Tr[m], q0 + 2);
            float cv3 = readlane_f(Tr[m], q0 + 3);
            float g = Tr[m] - (cv0 * nr[0] + cv1 * nr[1] + cv2 * nr[2] + cv3 * nr[3]);
            bool rowin = (((w * 16 + m) >> 2) == r);
            float gcol = -(cv0 * Bc[0] + cv1 * Bc[1] + cv2 * Bc[2] + cv3 * Bc[3]);
            if (rowin) g = nr[m & 3];
            if (colin) g = rowin ? Bc[m & 3] : gcol;
            Tr[m] = g;
        }
    }
#pragma unroll
    for (int m = 0; m < 16; ++m) T[(w * 16 + m) * 66 + jl] = Tr[m];
    __syncthreads();
}

// ---------------- K1: fused stats (blocks 512..519) + masked Grams (0..511) ----------------
__global__ __launch_bounds__(256) void k_front(const float* __restrict__ S,
                                               const int* __restrict__ lab,
                                               float* __restrict__ ws) {
    int b = blockIdx.x, tid = threadIdx.x;
    if (b >= 512) {
        __shared__ int slb[NS];
        __shared__ float r0[4][64], r1[4][64];
        __shared__ int rc[4];
        int bs = b - 512;
        for (int l = tid; l < NS; l += 256) slb[l] = lab[l];
        __syncthreads();
        int dl = tid & 63, ch = tid >> 6;
        int dd = bs * 64 + dl;
        float s0 = 0.f, s1 = 0.f;
        int n1 = 0;
        for (int n = ch * 128; n < ch * 128 + 128; ++n) {
            float v = S[n * DF + dd];
            if (slb[n]) { s1 += v; n1++; } else { s0 += v; }
        }
        r0[ch][dl] = s0; r1[ch][dl] = s1;
        if (dl == 0) rc[ch] = n1;
        __syncthreads();
        if (ch == 0) {
            float t0 = 0.f, t1 = 0.f; int n1t = 0;
#pragma unroll
            for (int x = 0; x < 4; ++x) { t0 += r0[x][dl]; t1 += r1[x][dl]; n1t += rc[x]; }
            float fn1 = (float)n1t, fn0 = (float)(NS - n1t);
            ws[WS_MEAN0 + dd] = t0 / fn0;
            ws[WS_MEAN1 + dd] = t1 / fn1;
            ws[WS_MEANA + dd] = (t0 + t1) / (float)NS;
            if (bs == 0 && dl == 0) {
                ws[WS_CNT] = fn0; ws[WS_CNT + 1] = fn1;
                ws[WS_KC] = 0.f; ws[WS_KC + 1] = 0.f;
            }
        }
        return;
    }
    __shared__ float SA[16 * 65];
    __shared__ float SB[16 * 65];
    __shared__ int lb[16];
    int tx = tid & 15, ty = tid >> 4;
    int i0 = (b & 7) * 64, j0 = ((b >> 3) & 7) * 64;
    int z = b >> 6;
    float a0[4][4] = {{0.f}}, a1[4][4] = {{0.f}};
    for (int nc = z * 64; nc < z * 64 + 64; nc += 16) {
#pragma unroll
        for (int l = 0; l < 4; ++l) {
            int idx = tid + 256 * l;
            int nn = idx >> 6, col = idx & 63;
            SA[nn * 65 + col] = S[(nc + nn) * DF + i0 + col];
            SB[nn * 65 + col] = S[(nc + nn) * DF + j0 + col];
        }
        if (tid < 16) lb[tid] = lab[nc + tid];
        __syncthreads();
#pragma unroll
        for (int kk = 0; kk < 16; ++kk) {
            float av[4], bv[4];
#pragma unroll
            for (int r = 0; r < 4; ++r) av[r] = SA[kk * 65 + ty * 4 + r];
#pragma unroll
            for (int s = 0; s < 4; ++s) bv[s] = SB[kk * 65 + tx * 4 + s];
            if (lb[kk]) {
#pragma unroll
                for (int r = 0; r < 4; ++r)
#pragma unroll
                    for (int s = 0; s < 4; ++s) a1[r][s] += av[r] * bv[s];
            } else {
#pragma unroll
                for (int r = 0; r < 4; ++r)
#pragma unroll
                    for (int s = 0; s < 4; ++s) a0[r][s] += av[r] * bv[s];
            }
        }
        __syncthreads();
    }
    float* Gp = ws + WS_GP;
#pragma unroll
    for (int r = 0; r < 4; ++r) {
        int i = i0 + ty * 4 + r;
#pragma unroll
        for (int s = 0; s < 4; ++s) {
            int j = j0 + tx * 4 + s;
            Gp[((z * 2 + 0) * DF + i) * DF + j] = a0[r][s];
            Gp[((z * 2 + 1) * DF + i) * DF + j] = a1[r][s];
        }
    }
}

// ---------------- K2: assemble M_c (64x64 tile blocks) + k=0 copies + pivot-0 inversions ----------------
// b<64: tile (ti=b>>3, tj=b&7), both classes; writes M and, for row-0/col-0
// tiles, the step-0 U/V copies (parity 0, aliasing dead PB). b==0 inverts its
// class-0 tile -> UC[0][0][slot 0]; b==64 recomputes tile(0,0) class 1 and
// inverts -> UC[0][1][slot 0]. All dependencies intra-block -> race-free.
__global__ __launch_bounds__(256) void k_asm(float* __restrict__ ws) {
    int b = blockIdx.x, tid = threadIdx.x;
    int tx = tid & 15, ty = tid >> 4;
    __shared__ float T[64 * 66];
    __shared__ float rbuf[2][4][64];
    const float* Gp = ws + WS_GP;
    float n0 = ws[WS_CNT], n1 = ws[WS_CNT + 1];
    float lam0 = fminf(n0 / (n0 + 1.f), 0.1f);
    float lam1 = fminf(n1 / (n1 + 1.f), 0.1f);
    bool dup = (b == 64);
    int ti = dup ? 0 : (b >> 3), tj = dup ? 0 : (b & 7);
    int jb = tj * 64 + tx * 4;
    float4 m0j = *(const float4*)&ws[WS_MEAN0 + jb];
    float4 m1j = *(const float4*)&ws[WS_MEAN1 + jb];
    float4 maj = *(const float4*)&ws[WS_MEANA + jb];
    float out0[4][4], out1[4][4];
#pragma unroll
    for (int r = 0; r < 4; ++r) {
        int i = ti * 64 + ty * 4 + r;
        float m0i = ws[WS_MEAN0 + i], m1i = ws[WS_MEAN1 + i], mai = ws[WS_MEANA + i];
        float4 g0 = make_float4(0.f, 0.f, 0.f, 0.f);
        float4 g1 = make_float4(0.f, 0.f, 0.f, 0.f);
#pragma unroll
        for (int ch = 0; ch < 8; ++ch) {
            float4 a = *(const float4*)&Gp[((ch * 2 + 0) * DF + i) * DF + jb];
            float4 bb = *(const float4*)&Gp[((ch * 2 + 1) * DF + i) * DF + jb];
            g0.x += a.x; g0.y += a.y; g0.z += a.z; g0.w += a.w;
            g1.x += bb.x; g1.y += bb.y; g1.z += bb.z; g1.w += bb.w;
        }
        float g0a[4] = {g0.x, g0.y, g0.z, g0.w};
        float g1a[4] = {g1.x, g1.y, g1.z, g1.w};
        float m0ja[4] = {m0j.x, m0j.y, m0j.z, m0j.w};
        float m1ja[4] = {m1j.x, m1j.y, m1j.z, m1j.w};
        float maja[4] = {maj.x, maj.y, maj.z, maj.w};
#pragma unroll
        for (int s = 0; s < 4; ++s) {
            int j = jb + s;
            float task = (g0a[s] + g1a[s] - (float)NS * mai * maja[s]) / (float)(NS - 1);
            float cov0 = (g0a[s] - n0 * m0i * m0ja[s]) / (n0 - 1.f);
            float cov1 = (g1a[s] - n1 * m1i * m1ja[s]) / (n1 - 1.f);
            float dg = (i == j) ? 0.1f : 0.f;
            out0[r][s] = lam0 * cov0 + (1.f - lam0) * task + dg;
            out1[r][s] = lam1 * cov1 + (1.f - lam1) * task + dg;
        }
    }
    if (!dup) {
#pragma unroll
        for (int r = 0; r < 4; ++r) {
            int i = ti * 64 + ty * 4 + r;
            *(float4*)&ws[WS_M + (size_t)i * DF + jb] = make_float4(out0[r][0], out0[r][1], out0[r][2], out0[r][3]);
            *(float4*)&ws[WS_M + DF * DF + (size_t)i * DF + jb] = make_float4(out1[r][0], out1[r][1], out1[r][2], out1[r][3]);
        }
        // step-0 copies (parity 0): U = M[0][tj], V = M[ti][0]
        if (ti == 0 && tj != 0) {
            float* u0 = ws + WS_UC + ((0 * 2 + 0) * 8 + tj) * 4096;
            float* u1 = ws + WS_UC + ((0 * 2 + 1) * 8 + tj) * 4096;
#pragma unroll
            for (int r = 0; r < 4; ++r) {
                int il = ty * 4 + r, jl = tx * 4;
                *(float4*)&u0[il * 64 + jl] = make_float4(out0[r][0], out0[r][1], out0[r][2], out0[r][3]);
                *(float4*)&u1[il * 64 + jl] = make_float4(out1[r][0], out1[r][1], out1[r][2], out1[r][3]);
            }
        }
        if (tj == 0 && ti != 0) {
            float* v0 = ws + WS_VC + ((0 * 2 + 0) * 8 + ti) * 4096;
            float* v1 = ws + WS_VC + ((0 * 2 + 1) * 8 + ti) * 4096;
#pragma unroll
            for (int r = 0; r < 4; ++r) {
                int il = ty * 4 + r, jl = tx * 4;
                *(float4*)&v0[il * 64 + jl] = make_float4(out0[r][0], out0[r][1], out0[r][2], out0[r][3]);
                *(float4*)&v1[il * 64 + jl] = make_float4(out1[r][0], out1[r][1], out1[r][2], out1[r][3]);
            }
        }
    }
    if (b == 0 || dup) {
        // invert own tile(0,0): class 0 for b==0, class 1 for b==64
#pragma unroll
        for (int r = 0; r < 4; ++r)
#pragma unroll
            for (int s = 0; s < 4; ++s)
                T[(ty * 4 + r) * 66 + tx * 4 + s] = dup ? out1[r][s] : out0[r][s];
        __syncthreads();
        gj_invert64(T, rbuf, tid);
        float* scr = ws + WS_UC + ((0 * 2 + (dup ? 1 : 0)) * 8 + 0) * 4096;   // T-hat_0 in slot 0
#pragma unroll
        for (int m = 0; m < 16; ++m) {
            int idx = tid + 256 * m;
            int i = idx >> 6, j = idx & 63;
            scr[i * 64 + j] = T[i * 66 + j];
        }
    }
}

// ---------------- K3: fused GJ step (ONE launch per k) ----------------
// Trailing blocks read U/V from parity copies (written last launch), so
// row/col blocks may overwrite M in the same launch. T-hat_k lives in UC
// slot k (never read as a U operand at step k). Blocks writing tiles in
// row/col k+1 also write next-parity copies; the special block (k+1,k+1)
// computes its trailing value, inverts it, and stores T-hat_{k+1} in UCo
// slot k+1 (written by no other block this step).
__global__ __launch_bounds__(256) void k_fgj(float* __restrict__ ws, int k) {
    int c = blockIdx.y, jh = blockIdx.z;
    int x = blockIdx.x;
    int ti = x >> 3, tj = x & 7;
    int par = k & 1, npar = par ^ 1;
    int tid = threadIdx.x;
    int cb0 = jh * 32;
    float* Mb = ws + WS_M + (size_t)c * DF * DF;
    const float* UCi = ws + WS_UC + (par * 2 + c) * 8 * 4096;
    const float* VCi = ws + WS_VC + (par * 2 + c) * 8 * 4096;
    float* UCo = ws + WS_UC + (npar * 2 + c) * 8 * 4096;
    float* VCo = ws + WS_VC + (npar * 2 + c) * 8 * 4096;
    const float* scr_in = UCi + k * 4096;       // T-hat_k

    if (ti == k && tj == k) {
        // diag: M[k][k] <- T-hat_k (half jh)
        float* Akk = Mb + (k * 64) * DF + k * 64;
#pragma unroll
        for (int m = 0; m < 8; ++m) {
            int idx = tid + 256 * m;     // 64 x 32
            int i = idx >> 5, j = idx & 31;
            Akk[i * DF + cb0 + j] = scr_in[i * 64 + cb0 + j];
        }
        return;
    }
    bool isrow = (ti == k);
    bool iscol = (tj == k);
    bool spec = (ti == k + 1) && (tj == k + 1);
    if ((iscol || spec) && jh == 1) return;

    __shared__ float T[64 * 68];
    __shared__ float V[64 * 66];
    __shared__ float U[64 * 68];
    __shared__ float D[64 * 68];
    __shared__ float rbuf[2][4][64];

    // stage T-hat (stride 68 -> float4 column reads aligned)
#pragma unroll
    for (int m = 0; m < 16; ++m) {
        int idx = tid + 256 * m;
        int i = idx >> 6, j = idx & 63;
        T[i * 68 + j] = scr_in[i * 64 + j];
    }

    if (isrow) {
        // row: M[k][tj] = T-hat * U_old (half jh)
        const float* uc = UCi + tj * 4096;
#pragma unroll
        for (int m = 0; m < 8; ++m) {
            int idx = tid + 256 * m;
            int i = idx >> 5, j = idx & 31;
            U[i * 68 + j] = uc[i * 64 + cb0 + j];
        }
        __syncthreads();
        int tx8 = tid & 7, ty32 = tid >> 3;
        float acc[2][4] = {{0.f}};
#pragma unroll 8
        for (int kk = 0; kk < 64; ++kk) {
            float a0 = T[(ty32 * 2 + 0) * 68 + kk];
            float a1 = T[(ty32 * 2 + 1) * 68 + kk];
            float4 bv = *(const float4*)&U[kk * 68 + tx8 * 4];
            acc[0][0] += a0 * bv.x; acc[0][1] += a0 * bv.y; acc[0][2] += a0 * bv.z; acc[0][3] += a0 * bv.w;
            acc[1][0] += a1 * bv.x; acc[1][1] += a1 * bv.y; acc[1][2] += a1 * bv.z; acc[1][3] += a1 * bv.w;
        }
        float* dst = Mb + (k * 64) * DF + tj * 64 + cb0;
#pragma unroll
        for (int r = 0; r < 2; ++r) {
            int row = ty32 * 2 + r;
            float4 o = make_float4(acc[r][0], acc[r][1], acc[r][2], acc[r][3]);
            *(float4*)&dst[row * DF + tx8 * 4] = o;
            if (tj == k + 1)
                *(float4*)&VCo[k * 4096 + row * 64 + cb0 + tx8 * 4] = o;
        }
        return;
    }

    if (iscol) {
        // col: M[ti][k] = -V_old * T-hat (full tile, one block)
        const float* vc = VCi + ti * 4096;
#pragma unroll
        for (int m = 0; m < 16; ++m) {
            int idx = tid + 256 * m;
            int i = idx >> 6, j = idx & 63;
            V[i * 66 + j] = vc[i * 64 + j];
        }
        __syncthreads();
        int tx16 = tid & 15, ty16 = tid >> 4;
        float acc[4][4] = {{0.f}};
#pragma unroll 8
        for (int kk = 0; kk < 64; ++kk) {
            float a[4];
#pragma unroll
            for (int r = 0; r < 4; ++r) a[r] = V[(ty16 * 4 + r) * 66 + kk];
            float4 bv = *(const float4*)&T[kk * 68 + tx16 * 4];
#pragma unroll
            for (int r = 0; r < 4; ++r) {
                acc[r][0] += a[r] * bv.x; acc[r][1] += a[r] * bv.y;
                acc[r][2] += a[r] * bv.z; acc[r][3] += a[r] * bv.w;
            }
        }
        float* dst = Mb + (ti * 64) * DF + k * 64;
#pragma unroll
        for (int r = 0; r < 4; ++r) {
            int row = ty16 * 4 + r;
            float4 o = make_float4(-acc[r][0], -acc[r][1], -acc[r][2], -acc[r][3]);
            *(float4*)&dst[row * DF + tx16 * 4] = o;
            if (ti == k + 1)
                *(float4*)&UCo[k * 4096 + row * 64 + tx16 * 4] = o;
        }
        return;
    }

    if (!spec) {
        // trailing half-tile: D = T-hat*U_half; Y -= V*D
        const float* vc = VCi + ti * 4096;
#pragma unroll
        for (int m = 0; m < 16; ++m) {
            int idx = tid + 256 * m;
            int i = idx >> 6, j = idx & 63;
            V[i * 66 + j] = vc[i * 64 + j];
        }
        const float* uc = UCi + tj * 4096;
#pragma unroll
        for (int m = 0; m < 8; ++m) {
            int idx = tid + 256 * m;
            int i = idx >> 5, j = idx & 31;
            U[i * 68 + j] = uc[i * 64 + cb0 + j];
        }
        __syncthreads();
        int tx8 = tid & 7, ty32 = tid >> 3;
        float a1[2][4] = {{0.f}};
#pragma unroll 8
        for (int kk = 0; kk < 64; ++kk) {
            float v0 = T[(ty32 * 2 + 0) * 68 + kk];
            float v1 = T[(ty32 * 2 + 1) * 68 + kk];
            float4 bv = *(const float4*)&U[kk * 68 + tx8 * 4];
            a1[0][0] += v0 * bv.x; a1[0][1] += v0 * bv.y; a1[0][2] += v0 * bv.z; a1[0][3] += v0 * bv.w;
            a1[1][0] += v1 * bv.x; a1[1][1] += v1 * bv.y; a1[1][2] += v1 * bv.z; a1[1][3] += v1 * bv.w;
        }
#pragma unroll
        for (int r = 0; r < 2; ++r)
            *(float4*)&D[(ty32 * 2 + r) * 68 + tx8 * 4] = make_float4(a1[r][0], a1[r][1], a1[r][2], a1[r][3]);
        __syncthreads();
        float a2[2][4] = {{0.f}};
#pragma unroll 8
        for (int kk = 0; kk < 64; ++kk) {
            float v0 = V[(ty32 * 2 + 0) * 66 + kk];
            float v1 = V[(ty32 * 2 + 1) * 66 + kk];
            float4 bv = *(const float4*)&D[kk * 68 + tx8 * 4];
            a2[0][0] += v0 * bv.x; a2[0][1] += v0 * bv.y; a2[0][2] += v0 * bv.z; a2[0][3] += v0 * bv.w;
            a2[1][0] += v1 * bv.x; a2[1][1] += v1 * bv.y; a2[1][2] += v1 * bv.z; a2[1][3] += v1 * bv.w;
        }
        float* dst = Mb + (ti * 64) * DF + tj * 64 + cb0;
#pragma unroll
        for (int r = 0; r < 2; ++r) {
            int row = ty32 * 2 + r;
            float4 old = *(const float4*)&dst[row * DF + tx8 * 4];
            float4 nv = make_float4(old.x - a2[r][0], old.y - a2[r][1], old.z - a2[r][2], old.w - a2[r][3]);
            *(float4*)&dst[row * DF + tx8 * 4] = nv;
            if (tj == k + 1)
                *(float4*)&VCo[ti * 4096 + row * 64 + cb0 + tx8 * 4] = nv;
            if (ti == k + 1)
                *(float4*)&UCo[tj * 4096 + row * 64 + cb0 + tx8 * 4] = nv;
        }
        return;
    }

    // special (k+1,k+1), exists only for k<7: full trailing value, then
    // invert -> UCo slot k+1 (= T-hat_{k+1}).
    {
        const float* vc = VCi + (k + 1) * 4096;
#pragma unroll
        for (int m = 0; m < 16; ++m) {
            int idx = tid + 256 * m;
            int i = idx >> 6, j = idx & 63;
            V[i * 66 + j] = vc[i * 64 + j];
        }
        const float* uc = UCi + (k + 1) * 4096;
#pragma unroll
        for (int m = 0; m < 16; ++m) {
            int idx = tid + 256 * m;
            int i = idx >> 6, j = idx & 63;
            U[i * 68 + j] = uc[i * 64 + j];
        }
        __syncthreads();
        int tx16 = tid & 15, ty16 = tid >> 4;
        float d[4][4] = {{0.f}};
#pragma unroll 8
        for (int kk = 0; kk < 64; ++kk) {
            float a[4];
#pragma unroll
            for (int r = 0; r < 4; ++r) a[r] = T[(ty16 * 4 + r) * 68 + kk];
            float4 bv = *(const float4*)&U[kk * 68 + tx16 * 4];
#pragma unroll
            for (int r = 0; r < 4; ++r) {
                d[r][0] += a[r] * bv.x; d[r][1] += a[r] * bv.y;
                d[r][2] += a[r] * bv.z; d[r][3] += a[r] * bv.w;
            }
        }
#pragma unroll
        for (int r = 0; r < 4; ++r)
            *(float4*)&D[(ty16 * 4 + r) * 68 + tx16 * 4] = make_float4(d[r][0], d[r][1], d[r][2], d[r][3]);
        __syncthreads();
        float y[4][4] = {{0.f}};
#pragma unroll 8
        for (int kk = 0; kk < 64; ++kk) {
            float a[4];
#pragma unroll
            for (int r = 0; r < 4; ++r) a[r] = V[(ty16 * 4 + r) * 66 + kk];
            float4 bv = *(const float4*)&D[kk * 68 + tx16 * 4];
#pragma unroll
            for (int r = 0; r < 4; ++r) {
                y[r][0] += a[r] * bv.x; y[r][1] += a[r] * bv.y;
                y[r][2] += a[r] * bv.z; y[r][3] += a[r] * bv.w;
            }
        }
        const float* dst = Mb + (size_t)((k + 1) * 64) * DF + (k + 1) * 64;
        float4 nv[4];
#pragma unroll
        for (int r = 0; r < 4; ++r) {
            int row = ty16 * 4 + r;
            float4 old = *(const float4*)&dst[row * DF + tx16 * 4];
            nv[r] = make_float4(old.x - y[r][0], old.y - y[r][1], old.z - y[r][2], old.w - y[r][3]);
        }
        __syncthreads();   // all V reads done before overwrite
#pragma unroll
        for (int r = 0; r < 4; ++r) {
            int row = ty16 * 4 + r;
            V[row * 66 + tx16 * 4 + 0] = nv[r].x;
            V[row * 66 + tx16 * 4 + 1] = nv[r].y;
            V[row * 66 + tx16 * 4 + 2] = nv[r].z;
            V[row * 66 + tx16 * 4 + 3] = nv[r].w;
        }
        __syncthreads();
        gj_invert64(V, rbuf, tid);
        float* so = UCo + (k + 1) * 4096;
#pragma unroll
        for (int m = 0; m < 16; ++m) {
            int idx = tid + 256 * m;
            int i = idx >> 6, j = idx & 63;
            so[i * 64 + j] = V[i * 66 + j];
        }
    }
}

// ---------------- K4: v_c/k_c (blocks 0..15) + P fp32 -> bf16 (blocks 16..271) ----------------
__global__ __launch_bounds__(256) void k_vkbf(float* __restrict__ ws) {
    int b = blockIdx.x;
    int tid = threadIdx.x;
    if (b >= 16) {
        // convert M [2][512][512] fp32 -> PB bf16 (overwrites the dead GJ scratch)
        int e = (b - 16) * 2048 + tid * 8;
        const float* M = ws + WS_M;
        unsigned short* pbw = (unsigned short*)(ws + WS_PB);
        float4 x0 = *(const float4*)&M[e];
        float4 x1 = *(const float4*)&M[e + 4];
        short8 r;
        r[0] = (short)f2bf(x0.x); r[1] = (short)f2bf(x0.y);
        r[2] = (short)f2bf(x0.z); r[3] = (short)f2bf(x0.w);
        r[4] = (short)f2bf(x1.x); r[5] = (short)f2bf(x1.y);
        r[6] = (short)f2bf(x1.z); r[7] = (short)f2bf(x1.w);
        *(short8*)(pbw + e) = r;
        return;
    }
    int c = b >> 3, rb = b & 7;
    const float* P = ws + WS_M + (size_t)c * DF * DF;
    const float* mc = ws + (c ? WS_MEAN1 : WS_MEAN0);
    float* v = ws + (c ? WS_V1 : WS_V0);
    __shared__ float ml[DF];
    __shared__ float red[4][64];
    for (int l = tid; l < DF; l += 256) ml[l] = mc[l];
    __syncthreads();
    int rl = tid & 63, ch = tid >> 6;
    int row = rb * 64 + rl;
    float dot = 0.f;
    const float* pr = P + (size_t)row * DF + ch * 128;
    for (int t = 0; t < 32; ++t) {
        float4 pv = *(const float4*)(pr + t * 4);
        const float* mm = ml + ch * 128 + t * 4;
        dot += pv.x * mm[0] + pv.y * mm[1] + pv.z * mm[2] + pv.w * mm[3];
    }
    red[ch][rl] = dot;
    __syncthreads();
    if (ch == 0) {
        float d = red[0][rl] + red[1][rl] + red[2][rl] + red[3][rl];
        v[row] = d;
        float kp = d * ml[row];
#pragma unroll
        for (int off = 32; off > 0; off >>= 1) kp += __shfl_down(kp, off);
        if (rl == 0) atomicAdd(&ws[WS_KC + c], kp);
    }
}

// ---------------- K5: fused Q->bf16 + logits init ----------------
__global__ __launch_bounds__(256) void k_qinit(const float* __restrict__ Q,
                                               float* __restrict__ ws,
                                               float* __restrict__ out) {
    unsigned short* qbw = (unsigned short*)(ws + WS_QB);
    const float* v0 = ws + WS_V0;
    const float* v1 = ws + WS_V1;
    int lane = threadIdx.x & 63;
    int q = blockIdx.x * 4 + (threadIdx.x >> 6);
    const float* qrow = Q + (size_t)q * DF + lane * 8;
    float4 x0 = *(const float4*)(qrow);
    float4 x1 = *(const float4*)(qrow + 4);
    const float* v0p = v0 + lane * 8;
    const float* v1p = v1 + lane * 8;
    float4 w00 = *(const float4*)(v0p), w01 = *(const float4*)(v0p + 4);
    float4 w10 = *(const float4*)(v1p), w11 = *(const float4*)(v1p + 4);
    float a0 = x0.x * w00.x + x0.y * w00.y + x0.z * w00.z + x0.w * w00.w
             + x1.x * w01.x + x1.y * w01.y + x1.z * w01.z + x1.w * w01.w;
    float a1 = x0.x * w10.x + x0.y * w10.y + x0.z * w10.z + x0.w * w10.w
             + x1.x * w11.x + x1.y * w11.y + x1.z * w11.z + x1.w * w11.w;
    short8 r;
    r[0] = (short)f2bf(x0.x); r[1] = (short)f2bf(x0.y);
    r[2] = (short)f2bf(x0.z); r[3] = (short)f2bf(x0.w);
    r[4] = (short)f2bf(x1.x); r[5] = (short)f2bf(x1.y);
    r[6] = (short)f2bf(x1.z); r[7] = (short)f2bf(x1.w);
    *(short8*)(qbw + (size_t)q * DF + lane * 8) = r;
#pragma unroll
    for (int off = 32; off > 0; off >>= 1) {
        a0 += __shfl_down(a0, off);
        a1 += __shfl_down(a1, off);
    }
    if (lane == 0) {
        out[q * 2 + 0] = 2.f * a0 - ws[WS_KC + 0];
        out[q * 2 + 1] = 2.f * a1 - ws[WS_KC + 1];
    }
}

// ---------------- K6: MFMA GEMM, 128x128 tile, LDS staging + swizzle ----------------
__global__ __launch_bounds__(256, 3) void k_gemm(const float* __restrict__ ws,
                                                 float* __restrict__ out) {
    const unsigned short* qb = (const unsigned short*)(ws + WS_QB);
    int c = blockIdx.y >> 2;
    int n0 = (blockIdx.y & 3) * 128;
    const unsigned short* pbc = (const unsigned short*)(ws + WS_PB) + (size_t)c * DF * DF;
    int q0 = blockIdx.x * 128;
    __shared__ __align__(16) unsigned short Abuf[128 * 64];   // 16 KB
    __shared__ __align__(16) unsigned short Bbuf[128 * 64];   // 16 KB
    int tid = threadIdx.x;
    int w = tid >> 6, lane = tid & 63;
    int quad = lane >> 4, l15 = lane & 15;
    floatx4 acc[2][8];
#pragma unroll
    for (int mt = 0; mt < 2; ++mt)
#pragma unroll
        for (int nt = 0; nt < 8; ++nt) acc[mt][nt] = (floatx4)(0.f);

    for (int kt = 0; kt < 8; ++kt) {
        int kc2 = kt * 64;
#pragma unroll
        for (int i = 0; i < 4; ++i) {
            int o = tid * 16 + i * 4096;
            int row = o >> 7;
            int sg = ((o >> 4) & 7) ^ (row & 7);
            load_lds16(qb + (size_t)(q0 + row) * DF + kc2 + sg * 8, (char*)Abuf + o);
        }
#pragma unroll
        for (int i = 0; i < 4; ++i) {
            int o = tid * 16 + i * 4096;
            int row = o >> 7;
            int sg = ((o >> 4) & 7) ^ (row & 7);
            load_lds16(pbc + (size_t)(n0 + row) * DF + kc2 + sg * 8, (char*)Bbuf + o);
        }
        __syncthreads();
#pragma unroll
        for (int kk2 = 0; kk2 < 2; ++kk2) {
            int u = ((kk2 * 4 + quad) ^ (l15 & 7)) << 4;   // swizzled 16B seg offset
            short8 b[8];
#pragma unroll
            for (int nt = 0; nt < 8; ++nt)
                b[nt] = *(const short8*)((const char*)Bbuf + (nt * 16 + l15) * 128 + u);
#pragma unroll
            for (int mt = 0; mt < 2; ++mt) {
                short8 a = *(const short8*)((const char*)Abuf + (w * 32 + mt * 16 + l15) * 128 + u);
#pragma unroll
                for (int nt = 0; nt < 8; ++nt)
                    acc[mt][nt] = __builtin_amdgcn_mfma_f32_16x16x32_bf16(a, b[nt], acc[mt][nt], 0, 0, 0);
            }
        }
        __syncthreads();
    }
#pragma unroll
    for (int mt = 0; mt < 2; ++mt)
#pragma unroll
        for (int reg = 0; reg < 4; ++reg) {
            int row = w * 32 + mt * 16 + quad * 4 + reg;
            float part = 0.f;
#pragma unroll
            for (int nt = 0; nt < 8; ++nt) {
                float h = acc[mt][nt][reg];
                unsigned qu = qb[(size_t)(q0 + row) * DF + n0 + nt * 16 + l15];
                part += h * __uint_as_float(qu << 16);
            }
            part += __shfl_xor(part, 1);
            part += __shfl_xor(part, 2);
            part += __shfl_xor(part, 4);
            part += __shfl_xor(part, 8);
            if (l15 == 0) atomicAdd(&out[(size_t)(q0 + row) * 2 + c], -part);
        }
}

extern "C" void kernel_launch(void* const* d_in, const int* in_sizes, int n_in,
                              void* d_out, int out_size, void* d_ws, size_t ws_size,
                              hipStream_t stream) {
    const float* S = (const float*)d_in[0];
    const int* lab = (const int*)d_in[1];
    const float* Q = (const float*)d_in[2];
    float* out = (float*)d_out;
    float* ws = (float*)d_ws;

    k_front<<<520, 256, 0, stream>>>(S, lab, ws);
    k_asm<<<65, 256, 0, stream>>>(ws);
    for (int k = 0; k < 8; ++k)
        k_fgj<<<dim3(64, 2, 2), 256, 0, stream>>>(ws, k);
    k_vkbf<<<272, 256, 0, stream>>>(ws);
    k_qinit<<<NQ / 4, 256, 0, stream>>>(Q, ws, out);
    k_gemm<<<dim3(NQ / 128, 8), 256, 0, stream>>>(ws, out);
}